// Round 2
// baseline (781.454 us; speedup 1.0000x reference)
//
#include <hip/hip_runtime.h>
#include <hip/hip_bf16.h>

#define NB 4
#define SL 2048
#define NG 16
#define NH 8
#define DH 64
#define NBH (NB * NH)

// ---------------------------------------------------------------------------
// K1: GEMM  X(Mtot,512) @ W(512,512) -> out
// MODE 0: heads layout  out[((b*NH+h)*n + i)*64 + e],  b=r/n, i=r%n, h=c/64, e=c%64
// MODE 1: plain          out[r*512 + c]
// ---------------------------------------------------------------------------
template <int MODE>
__global__ __launch_bounds__(256) void gemm512(const float* __restrict__ X,
                                               const float* __restrict__ Wm,
                                               float* __restrict__ out, int n) {
    __shared__ float As[16][65];  // [k][m], padded
    __shared__ float Bs[16][64];  // [k][n]
    const int t = threadIdx.x;
    const int rm = blockIdx.x * 64;
    const int cn = blockIdx.y * 64;
    const int tm = t >> 4, tn = t & 15;
    const int arow = t >> 2, ak = (t & 3) << 2;
    const int bk = t >> 4, bc = (t & 15) << 2;
    float acc[4][4] = {};
    for (int k0 = 0; k0 < 512; k0 += 16) {
        float4 av = *(const float4*)&X[(size_t)(rm + arow) * 512 + k0 + ak];
        float4 bv = *(const float4*)&Wm[(size_t)(k0 + bk) * 512 + cn + bc];
        __syncthreads();
        As[ak + 0][arow] = av.x;
        As[ak + 1][arow] = av.y;
        As[ak + 2][arow] = av.z;
        As[ak + 3][arow] = av.w;
        *(float4*)&Bs[bk][bc] = bv;
        __syncthreads();
#pragma unroll
        for (int kk = 0; kk < 16; ++kk) {
            float a0 = As[kk][tm * 4 + 0], a1 = As[kk][tm * 4 + 1];
            float a2 = As[kk][tm * 4 + 2], a3 = As[kk][tm * 4 + 3];
            float4 b = *(const float4*)&Bs[kk][tn * 4];
            acc[0][0] += a0 * b.x; acc[0][1] += a0 * b.y; acc[0][2] += a0 * b.z; acc[0][3] += a0 * b.w;
            acc[1][0] += a1 * b.x; acc[1][1] += a1 * b.y; acc[1][2] += a1 * b.z; acc[1][3] += a1 * b.w;
            acc[2][0] += a2 * b.x; acc[2][1] += a2 * b.y; acc[2][2] += a2 * b.z; acc[2][3] += a2 * b.w;
            acc[3][0] += a3 * b.x; acc[3][1] += a3 * b.y; acc[3][2] += a3 * b.z; acc[3][3] += a3 * b.w;
        }
    }
#pragma unroll
    for (int j = 0; j < 4; ++j) {
        const int r = rm + tm * 4 + j;
#pragma unroll
        for (int jj = 0; jj < 4; ++jj) {
            const int cc = cn + tn * 4 + jj;
            if (MODE == 0) {
                const int b = r / n, i = r % n;
                out[(((size_t)(b * NH) + (cc >> 6)) * n + i) * DH + (cc & 63)] = acc[j][jj];
            } else {
                out[(size_t)r * 512 + cc] = acc[j][jj];
            }
        }
    }
}

// ---------------------------------------------------------------------------
// K2a: w[b,h,i,g] = exp(cs[b,h,g,:] . ks[b,h,i,:])   stored (bh, i, g)
// grid (NBH, SL/128)
// ---------------------------------------------------------------------------
__global__ __launch_bounds__(256) void compute_w_kernel(const float* __restrict__ ks,
                                                        const float* __restrict__ cs,
                                                        float* __restrict__ wb) {
    const int bh = blockIdx.x;
    const int i0 = blockIdx.y * 128;
    __shared__ float Ks[128 * 64];
    __shared__ float Cs[16][65];
    const int t = threadIdx.x;
    const float* kbase = ks + ((size_t)bh * SL + i0) * DH;
#pragma unroll
    for (int p = 0; p < 8; ++p) {
        const int idx = (p * 256 + t) * 4;
        *(float4*)&Ks[idx] = *(const float4*)&kbase[idx];
    }
    const float* cbase = cs + (size_t)bh * NG * DH;
#pragma unroll
    for (int p = 0; p < 4; ++p) {
        const int idx = p * 256 + t;
        Cs[idx >> 6][idx & 63] = cbase[idx];
    }
    __syncthreads();
    const int g = t & 15;
    const int isub = t >> 4;
    for (int rr = 0; rr < 8; ++rr) {
        const int i = isub + rr * 16;
        float d = 0.f;
#pragma unroll 8
        for (int e = 0; e < 64; ++e) d += Ks[i * 64 + e] * Cs[g][e];
        wb[((size_t)bh * SL + i0 + i) * NG + g] = expf(d);
    }
}

// ---------------------------------------------------------------------------
// K2b: n[bhg, s] = inclusive cumsum over s of w[bh, s, g].  grid (NBH*NG)
// ---------------------------------------------------------------------------
__global__ __launch_bounds__(256) void scan_kernel(const float* __restrict__ wb,
                                                   float* __restrict__ nb) {
    const int bhg = blockIdx.x;
    const int bh = bhg >> 4, g = bhg & 15;
    __shared__ float sw[2048];
    __shared__ float sp[256];
    const int t = threadIdx.x;
    for (int p = 0; p < 8; ++p) {
        const int s = p * 256 + t;
        sw[s] = wb[((size_t)bh * SL + s) * NG + g];
    }
    __syncthreads();
    float loc[8];
    float run = 0.f;
#pragma unroll
    for (int j = 0; j < 8; ++j) { run += sw[t * 8 + j]; loc[j] = run; }
    sp[t] = run;
    __syncthreads();
    for (int off = 1; off < 256; off <<= 1) {
        const float v = sp[t];
        const float add = (t >= off) ? sp[t - off] : 0.f;
        __syncthreads();
        sp[t] = v + add;
        __syncthreads();
    }
    const float offs = (t > 0) ? sp[t - 1] : 0.f;
#pragma unroll
    for (int j = 0; j < 8; ++j)
        nb[(size_t)bhg * SL + t * 8 + j] = offs + loc[j];
}

// ---------------------------------------------------------------------------
// K3: logits[s,g] = causal(Q K^T) @ W ; then softmax over g, c = p/(sum*n)
// grid (NBH, SL/64)
// ---------------------------------------------------------------------------
__global__ __launch_bounds__(256) void pass1_kernel(const float* __restrict__ qs,
                                                    const float* __restrict__ ks,
                                                    const float* __restrict__ wb,
                                                    const float* __restrict__ nb,
                                                    float* __restrict__ cb) {
    const int bh = blockIdx.x;
    const int r = gridDim.y - 1 - blockIdx.y;  // big blocks launch first
    const int s0 = r * 64;
    __shared__ float Qs[64 * 64];
    __shared__ float Kt[64][65];
    __shared__ float At[64][65];
    __shared__ float Wt[64][17];
    __shared__ float Lg[64][17];
    const int t = threadIdx.x;
    const int am = t >> 4, an = t & 15;
    const float* qbase = qs + ((size_t)bh * SL + s0) * DH;
#pragma unroll
    for (int p = 0; p < 4; ++p) {
        const int idx = (p * 256 + t) * 4;
        *(float4*)&Qs[idx] = *(const float4*)&qbase[idx];
    }
    float lg[4] = {0.f, 0.f, 0.f, 0.f};
    for (int c = 0; c <= r; ++c) {
        __syncthreads();
        const float* kbase = ks + ((size_t)bh * SL + c * 64) * DH;
        for (int p = 0; p < 16; ++p) {
            const int idx = p * 256 + t;
            Kt[idx >> 6][idx & 63] = kbase[idx];
        }
        const float* wbase = wb + ((size_t)bh * SL + c * 64) * NG;
#pragma unroll
        for (int p = 0; p < 4; ++p) {
            const int idx = p * 256 + t;
            Wt[idx >> 4][idx & 15] = wbase[idx];
        }
        __syncthreads();
        float a[4][4] = {};
#pragma unroll 8
        for (int e = 0; e < 64; ++e) {
            float qv[4], kv[4];
#pragma unroll
            for (int j = 0; j < 4; ++j) qv[j] = Qs[(am * 4 + j) * 64 + e];
#pragma unroll
            for (int jj = 0; jj < 4; ++jj) kv[jj] = Kt[an * 4 + jj][e];
#pragma unroll
            for (int j = 0; j < 4; ++j)
#pragma unroll
                for (int jj = 0; jj < 4; ++jj) a[j][jj] += qv[j] * kv[jj];
        }
        if (c == r) {  // causal: keep i <= s
#pragma unroll
            for (int j = 0; j < 4; ++j)
#pragma unroll
                for (int jj = 0; jj < 4; ++jj)
                    if (an * 4 + jj > am * 4 + j) a[j][jj] = 0.f;
        }
#pragma unroll
        for (int j = 0; j < 4; ++j)
#pragma unroll
            for (int jj = 0; jj < 4; ++jj) At[am * 4 + j][an * 4 + jj] = a[j][jj];
        __syncthreads();
#pragma unroll 8
        for (int ii = 0; ii < 64; ++ii) {
            const float wv = Wt[ii][an];
#pragma unroll
            for (int j = 0; j < 4; ++j) lg[j] += At[am * 4 + j][ii] * wv;
        }
    }
    __syncthreads();
#pragma unroll
    for (int j = 0; j < 4; ++j) Lg[am * 4 + j][an] = lg[j];
    __syncthreads();
    if (t < 64) {
        const int s = s0 + t;
        const float* nbase = nb + (size_t)bh * NG * SL + s;
        float nv[16], l[16];
        float mx = -1e30f;
#pragma unroll
        for (int g = 0; g < 16; ++g) {
            nv[g] = nbase[(size_t)g * SL];
            l[g] = Lg[t][g] / nv[g];
            mx = fmaxf(mx, l[g]);
        }
        float sum = 0.f;
#pragma unroll
        for (int g = 0; g < 16; ++g) { l[g] = expf(l[g] - mx); sum += l[g]; }
        const float inv = 1.f / sum;
#pragma unroll
        for (int g = 0; g < 16; ++g)
            cb[((size_t)bh * SL + s) * NG + g] = l[g] * inv / nv[g];
    }
}

// ---------------------------------------------------------------------------
// K4: out[s,e] = causal(C W^T) @ V  -> oh in (B, S, 512) layout (col = h*64+e)
// grid (NBH, SL/64)
// ---------------------------------------------------------------------------
__global__ __launch_bounds__(256) void pass2_kernel(const float* __restrict__ cb,
                                                    const float* __restrict__ wb,
                                                    const float* __restrict__ vs,
                                                    float* __restrict__ oh) {
    const int bh = blockIdx.x;
    const int b = bh >> 3, h = bh & 7;
    const int r = gridDim.y - 1 - blockIdx.y;
    const int s0 = r * 64;
    __shared__ float Ct[64 * 16];
    __shared__ float Wt[64][17];
    __shared__ float Vt[64 * 64];
    __shared__ float St[64][65];
    const int t = threadIdx.x;
    const int am = t >> 4, an = t & 15;
    {
        const int idx = t * 4;
        *(float4*)&Ct[idx] = *(const float4*)&cb[((size_t)bh * SL + s0) * NG + idx];
    }
    float acc[4][4] = {};
    for (int c = 0; c <= r; ++c) {
        __syncthreads();
        const float* wbase = wb + ((size_t)bh * SL + c * 64) * NG;
#pragma unroll
        for (int p = 0; p < 4; ++p) {
            const int idx = p * 256 + t;
            Wt[idx >> 4][idx & 15] = wbase[idx];
        }
        const float* vbase = vs + ((size_t)bh * SL + c * 64) * DH;
#pragma unroll
        for (int p = 0; p < 4; ++p) {
            const int idx = (p * 256 + t) * 4;
            *(float4*)&Vt[idx] = *(const float4*)&vbase[idx];
        }
        __syncthreads();
        float sv[4][4] = {};
#pragma unroll
        for (int g = 0; g < 16; ++g) {
            float cv[4], wv[4];
#pragma unroll
            for (int j = 0; j < 4; ++j) cv[j] = Ct[(am * 4 + j) * 16 + g];
#pragma unroll
            for (int jj = 0; jj < 4; ++jj) wv[jj] = Wt[an * 4 + jj][g];
#pragma unroll
            for (int j = 0; j < 4; ++j)
#pragma unroll
                for (int jj = 0; jj < 4; ++jj) sv[j][jj] += cv[j] * wv[jj];
        }
        if (c == r) {
#pragma unroll
            for (int j = 0; j < 4; ++j)
#pragma unroll
                for (int jj = 0; jj < 4; ++jj)
                    if (an * 4 + jj > am * 4 + j) sv[j][jj] = 0.f;
        }
#pragma unroll
        for (int j = 0; j < 4; ++j)
#pragma unroll
            for (int jj = 0; jj < 4; ++jj) St[am * 4 + j][an * 4 + jj] = sv[j][jj];
        __syncthreads();
#pragma unroll 8
        for (int ii = 0; ii < 64; ++ii) {
            float vv[4], st[4];
#pragma unroll
            for (int jj = 0; jj < 4; ++jj) vv[jj] = Vt[ii * 64 + an * 4 + jj];
#pragma unroll
            for (int j = 0; j < 4; ++j) st[j] = St[am * 4 + j][ii];
#pragma unroll
            for (int j = 0; j < 4; ++j)
#pragma unroll
                for (int jj = 0; jj < 4; ++jj) acc[j][jj] += st[j] * vv[jj];
        }
    }
#pragma unroll
    for (int j = 0; j < 4; ++j) {
        const int s = s0 + am * 4 + j;
#pragma unroll
        for (int jj = 0; jj < 4; ++jj) {
            const int e = an * 4 + jj;
            oh[((size_t)b * SL + s) * 512 + h * DH + e] = acc[j][jj];
        }
    }
}

// ---------------------------------------------------------------------------
extern "C" void kernel_launch(void* const* d_in, const int* in_sizes, int n_in,
                              void* d_out, int out_size, void* d_ws, size_t ws_size,
                              hipStream_t stream) {
    const float* query   = (const float*)d_in[0];
    const float* key     = (const float*)d_in[1];
    const float* value   = (const float*)d_in[2];
    const float* context = (const float*)d_in[3];
    const float* qp = (const float*)d_in[4];
    const float* kp = (const float*)d_in[5];
    const float* vp = (const float*)d_in[6];
    const float* op = (const float*)d_in[7];
    const float* cp = (const float*)d_in[8];
    float* out = (float*)d_out;
    float* ws = (float*)d_ws;

    const size_t SZH = (size_t)NB * NH * SL * DH;  // 4,194,304 floats
    float* qs = ws;
    float* ks = qs + SZH;
    float* vs = ks + SZH;
    float* cs = vs + SZH;                              // NB*NH*NG*DH = 32,768
    float* wb = cs + (size_t)NB * NH * NG * DH;        // 1,048,576
    float* nb = wb + (size_t)NBH * SL * NG;            // 1,048,576
    float* cb = nb + (size_t)NBH * NG * SL;            // 1,048,576
    float* oh = qs;  // reuse qs buffer: pass1 (last reader of qs) precedes pass2

    dim3 blk(256);
    gemm512<0><<<dim3(128, 8), blk, 0, stream>>>(query, qp, qs, SL);
    gemm512<0><<<dim3(128, 8), blk, 0, stream>>>(key, kp, ks, SL);
    gemm512<0><<<dim3(128, 8), blk, 0, stream>>>(value, vp, vs, SL);
    gemm512<0><<<dim3(1, 8), blk, 0, stream>>>(context, cp, cs, NG);
    compute_w_kernel<<<dim3(NBH, SL / 128), blk, 0, stream>>>(ks, cs, wb);
    scan_kernel<<<dim3(NBH * NG), blk, 0, stream>>>(wb, nb);
    pass1_kernel<<<dim3(NBH, SL / 64), blk, 0, stream>>>(qs, ks, wb, nb, cb);
    pass2_kernel<<<dim3(NBH, SL / 64), blk, 0, stream>>>(cb, wb, vs, oh);
    gemm512<1><<<dim3(128, 8), blk, 0, stream>>>(oh, op, out, 1);
}

// Round 4
// 380.245 us; speedup vs baseline: 2.0551x; 2.0551x over previous
//
#include <hip/hip_runtime.h>
#include <hip/hip_bf16.h>

#define NB 4
#define SL 2048
#define NG 16
#define NH 8
#define DH 64
#define NBH (NB * NH)
#define NCH (SL / 64)  // 32 chunks of 64

// ---------------------------------------------------------------------------
// K1: GEMM  X(Mtot,512) @ W(512,512) -> out
// MODE 0: heads layout  out[((b*NH+h)*n + i)*64 + e];  MODE 1: plain out[r*512+c]
// ---------------------------------------------------------------------------
template <int MODE>
__global__ __launch_bounds__(256) void gemm512(const float* __restrict__ X,
                                               const float* __restrict__ Wm,
                                               float* __restrict__ out, int n) {
    __shared__ float As[16][65];  // [k][m], padded
    __shared__ float Bs[16][64];  // [k][n]
    const int t = threadIdx.x;
    const int rm = blockIdx.x * 64;
    const int cn = blockIdx.y * 64;
    const int tm = t >> 4, tn = t & 15;
    const int arow = t >> 2, ak = (t & 3) << 2;
    const int bk = t >> 4, bc = (t & 15) << 2;
    float acc[4][4] = {};
    for (int k0 = 0; k0 < 512; k0 += 16) {
        float4 av = *(const float4*)&X[(size_t)(rm + arow) * 512 + k0 + ak];
        float4 bv = *(const float4*)&Wm[(size_t)(k0 + bk) * 512 + cn + bc];
        __syncthreads();
        As[ak + 0][arow] = av.x;
        As[ak + 1][arow] = av.y;
        As[ak + 2][arow] = av.z;
        As[ak + 3][arow] = av.w;
        *(float4*)&Bs[bk][bc] = bv;
        __syncthreads();
#pragma unroll
        for (int kk = 0; kk < 16; ++kk) {
            float a0 = As[kk][tm * 4 + 0], a1 = As[kk][tm * 4 + 1];
            float a2 = As[kk][tm * 4 + 2], a3 = As[kk][tm * 4 + 3];
            float4 b = *(const float4*)&Bs[kk][tn * 4];
            acc[0][0] += a0 * b.x; acc[0][1] += a0 * b.y; acc[0][2] += a0 * b.z; acc[0][3] += a0 * b.w;
            acc[1][0] += a1 * b.x; acc[1][1] += a1 * b.y; acc[1][2] += a1 * b.z; acc[1][3] += a1 * b.w;
            acc[2][0] += a2 * b.x; acc[2][1] += a2 * b.y; acc[2][2] += a2 * b.z; acc[2][3] += a2 * b.w;
            acc[3][0] += a3 * b.x; acc[3][1] += a3 * b.y; acc[3][2] += a3 * b.z; acc[3][3] += a3 * b.w;
        }
    }
#pragma unroll
    for (int j = 0; j < 4; ++j) {
        const int r = rm + tm * 4 + j;
#pragma unroll
        for (int jj = 0; jj < 4; ++jj) {
            const int cc = cn + tn * 4 + jj;
            if (MODE == 0) {
                const int b = r / n, i = r % n;
                out[(((size_t)(b * NH) + (cc >> 6)) * n + i) * DH + (cc & 63)] = acc[j][jj];
            } else {
                out[(size_t)r * 512 + cc] = acc[j][jj];
            }
        }
    }
}

// ---------------------------------------------------------------------------
// K2a: w[bh,i,g] = exp(cs[bh,g,:] . ks[bh,i,:])   stored (bh, i, g)
// ---------------------------------------------------------------------------
__global__ __launch_bounds__(256) void compute_w_kernel(const float* __restrict__ ks,
                                                        const float* __restrict__ cs,
                                                        float* __restrict__ wb) {
    const int bh = blockIdx.x;
    const int i0 = blockIdx.y * 128;
    __shared__ float Ks[128 * 64];
    __shared__ float Cs[16][65];
    const int t = threadIdx.x;
    const float* kbase = ks + ((size_t)bh * SL + i0) * DH;
#pragma unroll
    for (int p = 0; p < 8; ++p) {
        const int idx = (p * 256 + t) * 4;
        *(float4*)&Ks[idx] = *(const float4*)&kbase[idx];
    }
    const float* cbase = cs + (size_t)bh * NG * DH;
#pragma unroll
    for (int p = 0; p < 4; ++p) {
        const int idx = p * 256 + t;
        Cs[idx >> 6][idx & 63] = cbase[idx];
    }
    __syncthreads();
    const int g = t & 15;
    const int isub = t >> 4;
    for (int rr = 0; rr < 8; ++rr) {
        const int i = isub + rr * 16;
        float d = 0.f;
#pragma unroll 8
        for (int e = 0; e < 64; ++e) d += Ks[i * 64 + e] * Cs[g][e];
        wb[((size_t)bh * SL + i0 + i) * NG + g] = expf(d);
    }
}

// ---------------------------------------------------------------------------
// K2b: n[bhg, s] = inclusive cumsum over s of w[bh, s, g].
// ---------------------------------------------------------------------------
__global__ __launch_bounds__(256) void scan_kernel(const float* __restrict__ wb,
                                                   float* __restrict__ nb) {
    const int bhg = blockIdx.x;
    const int bh = bhg >> 4, g = bhg & 15;
    __shared__ float sw[2048];
    __shared__ float sp[256];
    const int t = threadIdx.x;
    for (int p = 0; p < 8; ++p) {
        const int s = p * 256 + t;
        sw[s] = wb[((size_t)bh * SL + s) * NG + g];
    }
    __syncthreads();
    float loc[8];
    float run = 0.f;
#pragma unroll
    for (int j = 0; j < 8; ++j) { run += sw[t * 8 + j]; loc[j] = run; }
    sp[t] = run;
    __syncthreads();
    for (int off = 1; off < 256; off <<= 1) {
        const float v = sp[t];
        const float add = (t >= off) ? sp[t - off] : 0.f;
        __syncthreads();
        sp[t] = v + add;
        __syncthreads();
    }
    const float offs = (t > 0) ? sp[t - 1] : 0.f;
#pragma unroll
    for (int j = 0; j < 8; ++j)
        nb[(size_t)bhg * SL + t * 8 + j] = offs + loc[j];
}

// ---------------------------------------------------------------------------
// K3a: per-chunk state sums.  M_c[e,g] = sum_i K[i,e] W[i,g]  (64x16)
//                             N_c[g,e] = sum_i W[i,g] V[i,e]  (16x64)
// grid (NBH, NCH)
// ---------------------------------------------------------------------------
__global__ __launch_bounds__(256) void chunk_sums_kernel(const float* __restrict__ ks,
                                                         const float* __restrict__ wb,
                                                         const float* __restrict__ vs,
                                                         float* __restrict__ Mc,
                                                         float* __restrict__ Nc) {
    const int bh = blockIdx.x, c = blockIdx.y;
    __shared__ float Ks[64 * 64];
    __shared__ float Vs[64 * 64];
    __shared__ float Ws[64 * 16];
    const int t = threadIdx.x;
    const float* kbase = ks + ((size_t)bh * SL + c * 64) * DH;
    const float* vbase = vs + ((size_t)bh * SL + c * 64) * DH;
#pragma unroll
    for (int p = 0; p < 4; ++p) {
        const int idx = (p * 256 + t) * 4;
        *(float4*)&Ks[idx] = *(const float4*)&kbase[idx];
        *(float4*)&Vs[idx] = *(const float4*)&vbase[idx];
    }
    *(float4*)&Ws[t * 4] = *(const float4*)&wb[((size_t)bh * SL + c * 64) * NG + t * 4];
    __syncthreads();
    // M: e = t>>2 (broadcast over 4 lanes), g0 = (t&3)*4
    const int e = t >> 2, g0 = (t & 3) * 4;
    float m0 = 0.f, m1 = 0.f, m2 = 0.f, m3 = 0.f;
#pragma unroll 8
    for (int i = 0; i < 64; ++i) {
        const float kv = Ks[i * 64 + e];
        const float4 w = *(const float4*)&Ws[i * 16 + g0];
        m0 += kv * w.x; m1 += kv * w.y; m2 += kv * w.z; m3 += kv * w.w;
    }
    // N: g2 = t>>4 (broadcast), e2 = (t&15)*4
    const int g2 = t >> 4, e2 = (t & 15) * 4;
    float n0 = 0.f, n1 = 0.f, n2 = 0.f, n3 = 0.f;
#pragma unroll 8
    for (int i = 0; i < 64; ++i) {
        const float wv = Ws[i * 16 + g2];
        const float4 vv = *(const float4*)&Vs[i * 64 + e2];
        n0 += wv * vv.x; n1 += wv * vv.y; n2 += wv * vv.z; n3 += wv * vv.w;
    }
    float* mo = Mc + ((size_t)(bh * NCH + c) * 64 + e) * 16 + g0;
    mo[0] = m0; mo[1] = m1; mo[2] = m2; mo[3] = m3;
    float* no = Nc + ((size_t)(bh * NCH + c) * 16 + g2) * 64 + e2;
    no[0] = n0; no[1] = n1; no[2] = n2; no[3] = n3;
}

// ---------------------------------------------------------------------------
// K3b: in-place exclusive scan over chunks of the 1024-elem states.
// grid (2*NBH): even -> Mc, odd -> Nc.
// ---------------------------------------------------------------------------
__global__ __launch_bounds__(256) void scan_chunks_kernel(float* __restrict__ Mc,
                                                          float* __restrict__ Nc) {
    const int bh = blockIdx.x >> 1;
    float* base = ((blockIdx.x & 1) ? Nc : Mc) + (size_t)bh * NCH * 1024;
    const int t = threadIdx.x;
    float4 run = make_float4(0.f, 0.f, 0.f, 0.f);
    for (int c = 0; c < NCH; ++c) {
        float4* p = (float4*)&base[c * 1024 + t * 4];
        const float4 v = *p;
        *p = run;
        run.x += v.x; run.y += v.y; run.z += v.z; run.w += v.w;
    }
}

// ---------------------------------------------------------------------------
// K4: logits[s,g] = Q@P + causal(Q K^T)@W, /n, softmax over g, c = p/(sum*n)
// grid (NBH, NCH)
// ---------------------------------------------------------------------------
__global__ __launch_bounds__(256) void pass1c_kernel(const float* __restrict__ qs,
                                                     const float* __restrict__ ks,
                                                     const float* __restrict__ wb,
                                                     const float* __restrict__ nb,
                                                     const float* __restrict__ Mc,
                                                     float* __restrict__ cb) {
    const int bh = blockIdx.x;
    const int r = blockIdx.y;
    const int s0 = r * 64;
    __shared__ float Qs[64][65];
    __shared__ float Kt[64][65];
    __shared__ float At[64][65];
    __shared__ float Wt[64 * 16];
    __shared__ float Pt[64 * 16];
    __shared__ float Lg[64][17];
    const int t = threadIdx.x;
    const int am = t >> 4, an = t & 15;
    const float* qbase = qs + ((size_t)bh * SL + s0) * DH;
    const float* kbase = ks + ((size_t)bh * SL + s0) * DH;
#pragma unroll
    for (int p = 0; p < 4; ++p) {
        const int idx = (p * 256 + t) * 4;
        const int row = idx >> 6, col = idx & 63;
        const float4 qv = *(const float4*)&qbase[idx];
        Qs[row][col + 0] = qv.x; Qs[row][col + 1] = qv.y;
        Qs[row][col + 2] = qv.z; Qs[row][col + 3] = qv.w;
        const float4 kv = *(const float4*)&kbase[idx];
        Kt[row][col + 0] = kv.x; Kt[row][col + 1] = kv.y;
        Kt[row][col + 2] = kv.z; Kt[row][col + 3] = kv.w;
    }
    *(float4*)&Wt[t * 4] = *(const float4*)&wb[((size_t)bh * SL + s0) * NG + t * 4];
    *(float4*)&Pt[t * 4] = *(const float4*)&Mc[(size_t)(bh * NCH + r) * 1024 + t * 4];
    __syncthreads();
    // within-chunk causal QK^T
    float a[4][4] = {};
#pragma unroll 8
    for (int e = 0; e < 64; ++e) {
        float qv[4], kv[4];
#pragma unroll
        for (int j = 0; j < 4; ++j) qv[j] = Qs[am * 4 + j][e];
#pragma unroll
        for (int jj = 0; jj < 4; ++jj) kv[jj] = Kt[an * 4 + jj][e];
#pragma unroll
        for (int j = 0; j < 4; ++j)
#pragma unroll
            for (int jj = 0; jj < 4; ++jj) a[j][jj] += qv[j] * kv[jj];
    }
#pragma unroll
    for (int j = 0; j < 4; ++j)
#pragma unroll
        for (int jj = 0; jj < 4; ++jj) {
            if (an * 4 + jj > am * 4 + j) a[j][jj] = 0.f;  // causal within chunk
            At[am * 4 + j][an * 4 + jj] = a[j][jj];
        }
    __syncthreads();
    float lg[4] = {0.f, 0.f, 0.f, 0.f};
#pragma unroll 8
    for (int ii = 0; ii < 64; ++ii) {
        const float wv = Wt[ii * 16 + an];
#pragma unroll
        for (int j = 0; j < 4; ++j) lg[j] += At[am * 4 + j][ii] * wv;
    }
#pragma unroll 8
    for (int e = 0; e < 64; ++e) {
        const float pv = Pt[e * 16 + an];
#pragma unroll
        for (int j = 0; j < 4; ++j) lg[j] += Qs[am * 4 + j][e] * pv;
    }
#pragma unroll
    for (int j = 0; j < 4; ++j) Lg[am * 4 + j][an] = lg[j];
    __syncthreads();
    if (t < 64) {
        const int s = s0 + t;
        const float* nbase = nb + (size_t)bh * NG * SL + s;
        float nv[16], l[16];
        float mx = -1e30f;
#pragma unroll
        for (int g = 0; g < 16; ++g) {
            nv[g] = nbase[(size_t)g * SL];
            l[g] = Lg[t][g] / nv[g];
            mx = fmaxf(mx, l[g]);
        }
        float sum = 0.f;
#pragma unroll
        for (int g = 0; g < 16; ++g) { l[g] = expf(l[g] - mx); sum += l[g]; }
        const float inv = 1.f / sum;
#pragma unroll
        for (int g = 0; g < 16; ++g)
            cb[((size_t)bh * SL + s) * NG + g] = l[g] * inv / nv[g];
    }
}

// ---------------------------------------------------------------------------
// K5: out[s,e] = C@U + causal(C W^T)@V  -> oh (B,S,512)
// grid (NBH, NCH)
// ---------------------------------------------------------------------------
__global__ __launch_bounds__(256) void pass2c_kernel(const float* __restrict__ cb,
                                                     const float* __restrict__ wb,
                                                     const float* __restrict__ vs,
                                                     const float* __restrict__ Nc,
                                                     float* __restrict__ oh) {
    const int bh = blockIdx.x;
    const int b = bh >> 3, h = bh & 7;
    const int r = blockIdx.y;
    const int s0 = r * 64;
    __shared__ float Ct[64][17];
    __shared__ float Wt[64][17];
    __shared__ float Vt[64 * 64];
    __shared__ float St[64][65];
    __shared__ float Ut[16 * 64];
    const int t = threadIdx.x;
    const int am = t >> 4, an = t & 15;
    {
        const int idx = t * 4;
        const int row = idx >> 4, g0 = idx & 15;
        const float4 cv = *(const float4*)&cb[((size_t)bh * SL + s0) * NG + idx];
        Ct[row][g0 + 0] = cv.x; Ct[row][g0 + 1] = cv.y;
        Ct[row][g0 + 2] = cv.z; Ct[row][g0 + 3] = cv.w;
        const float4 wv = *(const float4*)&wb[((size_t)bh * SL + s0) * NG + idx];
        Wt[row][g0 + 0] = wv.x; Wt[row][g0 + 1] = wv.y;
        Wt[row][g0 + 2] = wv.z; Wt[row][g0 + 3] = wv.w;
    }
    const float* vbase = vs + ((size_t)bh * SL + s0) * DH;
#pragma unroll
    for (int p = 0; p < 4; ++p) {
        const int idx = (p * 256 + t) * 4;
        *(float4*)&Vt[idx] = *(const float4*)&vbase[idx];
    }
    *(float4*)&Ut[t * 4] = *(const float4*)&Nc[(size_t)(bh * NCH + r) * 1024 + t * 4];
    __syncthreads();
    // S = causal(C W^T) within chunk
    float sv[4][4] = {};
#pragma unroll
    for (int g = 0; g < 16; ++g) {
        float cv[4], wv[4];
#pragma unroll
        for (int j = 0; j < 4; ++j) cv[j] = Ct[am * 4 + j][g];
#pragma unroll
        for (int jj = 0; jj < 4; ++jj) wv[jj] = Wt[an * 4 + jj][g];
#pragma unroll
        for (int j = 0; j < 4; ++j)
#pragma unroll
            for (int jj = 0; jj < 4; ++jj) sv[j][jj] += cv[j] * wv[jj];
    }
#pragma unroll
    for (int j = 0; j < 4; ++j)
#pragma unroll
        for (int jj = 0; jj < 4; ++jj) {
            if (an * 4 + jj > am * 4 + j) sv[j][jj] = 0.f;
            St[am * 4 + j][an * 4 + jj] = sv[j][jj];
        }
    __syncthreads();
    float acc[4][4] = {};
#pragma unroll
    for (int g = 0; g < 16; ++g) {
        const float4 u = *(const float4*)&Ut[g * 64 + an * 4];
        float cv[4];
#pragma unroll
        for (int j = 0; j < 4; ++j) cv[j] = Ct[am * 4 + j][g];
#pragma unroll
        for (int j = 0; j < 4; ++j) {
            acc[j][0] += cv[j] * u.x; acc[j][1] += cv[j] * u.y;
            acc[j][2] += cv[j] * u.z; acc[j][3] += cv[j] * u.w;
        }
    }
#pragma unroll 8
    for (int ii = 0; ii < 64; ++ii) {
        const float4 vv = *(const float4*)&Vt[ii * 64 + an * 4];
        float st[4];
#pragma unroll
        for (int j = 0; j < 4; ++j) st[j] = St[am * 4 + j][ii];
#pragma unroll
        for (int j = 0; j < 4; ++j) {
            acc[j][0] += st[j] * vv.x; acc[j][1] += st[j] * vv.y;
            acc[j][2] += st[j] * vv.z; acc[j][3] += st[j] * vv.w;
        }
    }
#pragma unroll
    for (int j = 0; j < 4; ++j) {
        const int s = s0 + am * 4 + j;
        float* o = &oh[((size_t)b * SL + s) * 512 + h * DH + an * 4];
        o[0] = acc[j][0]; o[1] = acc[j][1]; o[2] = acc[j][2]; o[3] = acc[j][3];
    }
}

// ---------------------------------------------------------------------------
extern "C" void kernel_launch(void* const* d_in, const int* in_sizes, int n_in,
                              void* d_out, int out_size, void* d_ws, size_t ws_size,
                              hipStream_t stream) {
    const float* query   = (const float*)d_in[0];
    const float* key     = (const float*)d_in[1];
    const float* value   = (const float*)d_in[2];
    const float* context = (const float*)d_in[3];
    const float* qp = (const float*)d_in[4];
    const float* kp = (const float*)d_in[5];
    const float* vp = (const float*)d_in[6];
    const float* op = (const float*)d_in[7];
    const float* cp = (const float*)d_in[8];
    float* out = (float*)d_out;
    float* ws = (float*)d_ws;

    const size_t SZH = (size_t)NB * NH * SL * DH;      // 4,194,304 floats
    float* qs = ws;
    float* ks = qs + SZH;
    float* vs = ks + SZH;
    float* cs = vs + SZH;                              // 32,768
    float* wb = cs + (size_t)NB * NH * NG * DH;        // 1,048,576
    float* nb = wb + (size_t)NBH * SL * NG;            // 1,048,576
    float* cb = nb + (size_t)NBH * NG * SL;            // 1,048,576
    float* Mc = cb + (size_t)NBH * SL * NG;            // NBH*NCH*1024 = 1,048,576
    float* Nc = Mc + (size_t)NBH * NCH * 1024;         // 1,048,576
    float* oh = qs;  // reuse: pass1c is the last reader of qs

    dim3 blk(256);
    gemm512<0><<<dim3(128, 8), blk, 0, stream>>>(query, qp, qs, SL);
    gemm512<0><<<dim3(128, 8), blk, 0, stream>>>(key, kp, ks, SL);
    gemm512<0><<<dim3(128, 8), blk, 0, stream>>>(value, vp, vs, SL);
    gemm512<0><<<dim3(1, 8), blk, 0, stream>>>(context, cp, cs, NG);
    compute_w_kernel<<<dim3(NBH, SL / 128), blk, 0, stream>>>(ks, cs, wb);
    scan_kernel<<<dim3(NBH * NG), blk, 0, stream>>>(wb, nb);
    chunk_sums_kernel<<<dim3(NBH, NCH), blk, 0, stream>>>(ks, wb, vs, Mc, Nc);
    scan_chunks_kernel<<<dim3(NBH * 2), blk, 0, stream>>>(Mc, Nc);
    pass1c_kernel<<<dim3(NBH, NCH), blk, 0, stream>>>(qs, ks, wb, nb, Mc, cb);
    pass2c_kernel<<<dim3(NBH, NCH), blk, 0, stream>>>(cb, wb, vs, Nc, oh);
    gemm512<1><<<dim3(128, 8), blk, 0, stream>>>(oh, op, out, 1);
}

// Round 5
// 207.691 us; speedup vs baseline: 3.7626x; 1.8308x over previous
//
#include <hip/hip_runtime.h>
#include <hip/hip_bf16.h>

#define NB 4
#define SL 2048
#define NG 16
#define NH 8
#define DH 64
#define NBH (NB * NH)
#define NCH (SL / 64)  // 32 chunks of 64

typedef __attribute__((ext_vector_type(8))) short bh8;
typedef __attribute__((ext_vector_type(4))) float fx4;

__device__ __forceinline__ ushort f2bf(float x) {
    union { float f; unsigned u; } v; v.f = x;
    const unsigned r = v.u + 0x7fffu + ((v.u >> 16) & 1u);  // RNE
    return (ushort)(r >> 16);
}

// ---------------------------------------------------------------------------
// f32 -> bf16 elementwise, n/4 float4s.  grid 4096 x 256 covers 4,194,304.
// ---------------------------------------------------------------------------
__global__ __launch_bounds__(256) void conv_bf16(const float4* __restrict__ in,
                                                 ushort4* __restrict__ outp) {
    const int i = blockIdx.x * 256 + threadIdx.x;
    const float4 v = in[i];
    ushort4 o;
    o.x = f2bf(v.x); o.y = f2bf(v.y); o.z = f2bf(v.z); o.w = f2bf(v.w);
    outp[i] = o;
}

// ---------------------------------------------------------------------------
// W (512x512 f32, row-major [e][d]) -> WT (512x512 bf16, [d][e])
// ---------------------------------------------------------------------------
__global__ __launch_bounds__(256) void convT512(const float* __restrict__ W,
                                                ushort* __restrict__ WT) {
    __shared__ float tile[32][33];
    const int bx = blockIdx.x * 32, by = blockIdx.y * 32;
    const int tx = threadIdx.x & 31, ty = threadIdx.x >> 5;
#pragma unroll
    for (int p = 0; p < 4; ++p)
        tile[ty + p * 8][tx] = W[(size_t)(by + ty + p * 8) * 512 + bx + tx];
    __syncthreads();
#pragma unroll
    for (int p = 0; p < 4; ++p)
        WT[(size_t)(bx + ty + p * 8) * 512 + by + tx] = f2bf(tile[tx][ty + p * 8]);
}

// ---------------------------------------------------------------------------
// MFMA GEMM: A (Mx512 bf16 row-major) @ BT^T, BT is (512x512 bf16, [n][k]).
// f32 out.  MODE 0: heads layout; MODE 1: plain row-major Mx512.
// 128x128 tile, BK=32, 4 waves each owning a 64x64 quadrant (4x4 of 16x16).
// ---------------------------------------------------------------------------
template <int MODE>
__global__ __launch_bounds__(256) void gemm_mfma(const ushort* __restrict__ A,
                                                 const ushort* __restrict__ BT,
                                                 float* __restrict__ out, int n) {
    __shared__ __align__(16) ushort As[128 * 32];
    __shared__ __align__(16) ushort Bs[128 * 32];
    const int t = threadIdx.x;
    const int lane = t & 63, w = t >> 6;
    const int bm = blockIdx.x * 128, bn = blockIdx.y * 128;
    // staging: wave w fills LDS elems [w*1024, w*1024+1024) via 2 insts of 16B/lane
    const int e0 = w * 1024 + lane * 8;
    const int e1 = e0 + 512;
    const int r0 = e0 >> 5, c0 = e0 & 31;
    const int r1 = e1 >> 5, c1 = e1 & 31;
    const size_t a0 = (size_t)(bm + r0) * 512 + c0;
    const size_t a1 = (size_t)(bm + r1) * 512 + c1;
    const size_t b0 = (size_t)(bn + r0) * 512 + c0;
    const size_t b1 = (size_t)(bn + r1) * 512 + c1;
    const int wr = w >> 1, wc = w & 1;
    const int fr = lane & 15, kg = lane >> 4;
    const int aoff = (wr * 64 + fr) * 32 + kg * 8;
    const int boff = (wc * 64 + fr) * 32 + kg * 8;
    fx4 acc[4][4] = {};
    for (int k0 = 0; k0 < 512; k0 += 32) {
        __builtin_amdgcn_global_load_lds(
            (const __attribute__((address_space(1))) void*)(A + a0 + k0),
            (__attribute__((address_space(3))) void*)&As[w * 1024], 16, 0, 0);
        __builtin_amdgcn_global_load_lds(
            (const __attribute__((address_space(1))) void*)(A + a1 + k0),
            (__attribute__((address_space(3))) void*)&As[w * 1024 + 512], 16, 0, 0);
        __builtin_amdgcn_global_load_lds(
            (const __attribute__((address_space(1))) void*)(BT + b0 + k0),
            (__attribute__((address_space(3))) void*)&Bs[w * 1024], 16, 0, 0);
        __builtin_amdgcn_global_load_lds(
            (const __attribute__((address_space(1))) void*)(BT + b1 + k0),
            (__attribute__((address_space(3))) void*)&Bs[w * 1024 + 512], 16, 0, 0);
        __syncthreads();
        bh8 af[4], bf[4];
#pragma unroll
        for (int m = 0; m < 4; ++m) af[m] = *(const bh8*)&As[aoff + m * 512];
#pragma unroll
        for (int nn = 0; nn < 4; ++nn) bf[nn] = *(const bh8*)&Bs[boff + nn * 512];
#pragma unroll
        for (int m = 0; m < 4; ++m)
#pragma unroll
            for (int nn = 0; nn < 4; ++nn)
                acc[m][nn] = __builtin_amdgcn_mfma_f32_16x16x32_bf16(
                    af[m], bf[nn], acc[m][nn], 0, 0, 0);
        __syncthreads();
    }
#pragma unroll
    for (int m = 0; m < 4; ++m)
#pragma unroll
        for (int nn = 0; nn < 4; ++nn)
#pragma unroll
            for (int j = 0; j < 4; ++j) {
                const int r = bm + wr * 64 + m * 16 + kg * 4 + j;
                const int cc = bn + wc * 64 + nn * 16 + fr;
                if (MODE == 0) {
                    const int b = r / n, i = r % n;
                    out[(((size_t)(b * NH) + (cc >> 6)) * n + i) * DH + (cc & 63)] =
                        acc[m][nn][j];
                } else {
                    out[(size_t)r * 512 + cc] = acc[m][nn][j];
                }
            }
}

// ---------------------------------------------------------------------------
// f32 GEMM (kept for tiny context projection).  MODE 0 heads layout.
// ---------------------------------------------------------------------------
template <int MODE>
__global__ __launch_bounds__(256) void gemm512(const float* __restrict__ X,
                                               const float* __restrict__ Wm,
                                               float* __restrict__ out, int n) {
    __shared__ float As[16][65];
    __shared__ float Bs[16][64];
    const int t = threadIdx.x;
    const int rm = blockIdx.x * 64;
    const int cn = blockIdx.y * 64;
    const int tm = t >> 4, tn = t & 15;
    const int arow = t >> 2, ak = (t & 3) << 2;
    const int bk = t >> 4, bc = (t & 15) << 2;
    float acc[4][4] = {};
    for (int k0 = 0; k0 < 512; k0 += 16) {
        float4 av = *(const float4*)&X[(size_t)(rm + arow) * 512 + k0 + ak];
        float4 bv = *(const float4*)&Wm[(size_t)(k0 + bk) * 512 + cn + bc];
        __syncthreads();
        As[ak + 0][arow] = av.x;
        As[ak + 1][arow] = av.y;
        As[ak + 2][arow] = av.z;
        As[ak + 3][arow] = av.w;
        *(float4*)&Bs[bk][bc] = bv;
        __syncthreads();
#pragma unroll
        for (int kk = 0; kk < 16; ++kk) {
            float a0 = As[kk][tm * 4 + 0], a1 = As[kk][tm * 4 + 1];
            float a2 = As[kk][tm * 4 + 2], a3 = As[kk][tm * 4 + 3];
            float4 b = *(const float4*)&Bs[kk][tn * 4];
            acc[0][0] += a0 * b.x; acc[0][1] += a0 * b.y; acc[0][2] += a0 * b.z; acc[0][3] += a0 * b.w;
            acc[1][0] += a1 * b.x; acc[1][1] += a1 * b.y; acc[1][2] += a1 * b.z; acc[1][3] += a1 * b.w;
            acc[2][0] += a2 * b.x; acc[2][1] += a2 * b.y; acc[2][2] += a2 * b.z; acc[2][3] += a2 * b.w;
            acc[3][0] += a3 * b.x; acc[3][1] += a3 * b.y; acc[3][2] += a3 * b.z; acc[3][3] += a3 * b.w;
        }
    }
#pragma unroll
    for (int j = 0; j < 4; ++j) {
        const int r = rm + tm * 4 + j;
#pragma unroll
        for (int jj = 0; jj < 4; ++jj) {
            const int cc = cn + tn * 4 + jj;
            if (MODE == 0) {
                const int b = r / n, i = r % n;
                out[(((size_t)(b * NH) + (cc >> 6)) * n + i) * DH + (cc & 63)] = acc[j][jj];
            } else {
                out[(size_t)r * 512 + cc] = acc[j][jj];
            }
        }
    }
}

// ---------------------------------------------------------------------------
// w[bh,i,g] = exp(cs[bh,g,:] . ks[bh,i,:])   stored (bh, i, g)
// ---------------------------------------------------------------------------
__global__ __launch_bounds__(256) void compute_w_kernel(const float* __restrict__ ks,
                                                        const float* __restrict__ cs,
                                                        float* __restrict__ wb) {
    const int bh = blockIdx.x;
    const int i0 = blockIdx.y * 128;
    __shared__ float Ks[128 * 64];
    __shared__ float Cs[16][65];
    const int t = threadIdx.x;
    const float* kbase = ks + ((size_t)bh * SL + i0) * DH;
#pragma unroll
    for (int p = 0; p < 8; ++p) {
        const int idx = (p * 256 + t) * 4;
        *(float4*)&Ks[idx] = *(const float4*)&kbase[idx];
    }
    const float* cbase = cs + (size_t)bh * NG * DH;
#pragma unroll
    for (int p = 0; p < 4; ++p) {
        const int idx = p * 256 + t;
        Cs[idx >> 6][idx & 63] = cbase[idx];
    }
    __syncthreads();
    const int g = t & 15;
    const int isub = t >> 4;
    for (int rr = 0; rr < 8; ++rr) {
        const int i = isub + rr * 16;
        float d = 0.f;
#pragma unroll 8
        for (int e = 0; e < 64; ++e) d += Ks[i * 64 + e] * Cs[g][e];
        wb[((size_t)bh * SL + i0 + i) * NG + g] = expf(d);
    }
}

// ---------------------------------------------------------------------------
// n[bhg, s] = inclusive cumsum over s of w[bh, s, g].
// ---------------------------------------------------------------------------
__global__ __launch_bounds__(256) void scan_kernel(const float* __restrict__ wb,
                                                   float* __restrict__ nb) {
    const int bhg = blockIdx.x;
    const int bh = bhg >> 4, g = bhg & 15;
    __shared__ float sw[2048];
    __shared__ float sp[256];
    const int t = threadIdx.x;
    for (int p = 0; p < 8; ++p) {
        const int s = p * 256 + t;
        sw[s] = wb[((size_t)bh * SL + s) * NG + g];
    }
    __syncthreads();
    float loc[8];
    float run = 0.f;
#pragma unroll
    for (int j = 0; j < 8; ++j) { run += sw[t * 8 + j]; loc[j] = run; }
    sp[t] = run;
    __syncthreads();
    for (int off = 1; off < 256; off <<= 1) {
        const float v = sp[t];
        const float add = (t >= off) ? sp[t - off] : 0.f;
        __syncthreads();
        sp[t] = v + add;
        __syncthreads();
    }
    const float offs = (t > 0) ? sp[t - 1] : 0.f;
#pragma unroll
    for (int j = 0; j < 8; ++j)
        nb[(size_t)bhg * SL + t * 8 + j] = offs + loc[j];
}

// ---------------------------------------------------------------------------
// per-chunk state sums.  M_c[e,g] (64x16), N_c[g,e] (16x64)
// ---------------------------------------------------------------------------
__global__ __launch_bounds__(256) void chunk_sums_kernel(const float* __restrict__ ks,
                                                         const float* __restrict__ wb,
                                                         const float* __restrict__ vs,
                                                         float* __restrict__ Mc,
                                                         float* __restrict__ Nc) {
    const int bh = blockIdx.x, c = blockIdx.y;
    __shared__ float Ks[64 * 64];
    __shared__ float Vs[64 * 64];
    __shared__ float Ws[64 * 16];
    const int t = threadIdx.x;
    const float* kbase = ks + ((size_t)bh * SL + c * 64) * DH;
    const float* vbase = vs + ((size_t)bh * SL + c * 64) * DH;
#pragma unroll
    for (int p = 0; p < 4; ++p) {
        const int idx = (p * 256 + t) * 4;
        *(float4*)&Ks[idx] = *(const float4*)&kbase[idx];
        *(float4*)&Vs[idx] = *(const float4*)&vbase[idx];
    }
    *(float4*)&Ws[t * 4] = *(const float4*)&wb[((size_t)bh * SL + c * 64) * NG + t * 4];
    __syncthreads();
    const int e = t >> 2, g0 = (t & 3) * 4;
    float m0 = 0.f, m1 = 0.f, m2 = 0.f, m3 = 0.f;
#pragma unroll 8
    for (int i = 0; i < 64; ++i) {
        const float kv = Ks[i * 64 + e];
        const float4 w = *(const float4*)&Ws[i * 16 + g0];
        m0 += kv * w.x; m1 += kv * w.y; m2 += kv * w.z; m3 += kv * w.w;
    }
    const int g2 = t >> 4, e2 = (t & 15) * 4;
    float n0 = 0.f, n1 = 0.f, n2 = 0.f, n3 = 0.f;
#pragma unroll 8
    for (int i = 0; i < 64; ++i) {
        const float wv = Ws[i * 16 + g2];
        const float4 vv = *(const float4*)&Vs[i * 64 + e2];
        n0 += wv * vv.x; n1 += wv * vv.y; n2 += wv * vv.z; n3 += wv * vv.w;
    }
    float* mo = Mc + ((size_t)(bh * NCH + c) * 64 + e) * 16 + g0;
    mo[0] = m0; mo[1] = m1; mo[2] = m2; mo[3] = m3;
    float* no = Nc + ((size_t)(bh * NCH + c) * 16 + g2) * 64 + e2;
    no[0] = n0; no[1] = n1; no[2] = n2; no[3] = n3;
}

// ---------------------------------------------------------------------------
// in-place exclusive scan over chunks of the 1024-elem states.
// ---------------------------------------------------------------------------
__global__ __launch_bounds__(256) void scan_chunks_kernel(float* __restrict__ Mc,
                                                          float* __restrict__ Nc) {
    const int bh = blockIdx.x >> 1;
    float* base = ((blockIdx.x & 1) ? Nc : Mc) + (size_t)bh * NCH * 1024;
    const int t = threadIdx.x;
    float4 run = make_float4(0.f, 0.f, 0.f, 0.f);
    for (int c = 0; c < NCH; ++c) {
        float4* p = (float4*)&base[c * 1024 + t * 4];
        const float4 v = *p;
        *p = run;
        run.x += v.x; run.y += v.y; run.z += v.z; run.w += v.w;
    }
}

// ---------------------------------------------------------------------------
// logits[s,g] = Q@P + causal(Q K^T)@W, /n, softmax over g, c = p/(sum*n)
// ---------------------------------------------------------------------------
__global__ __launch_bounds__(256) void pass1c_kernel(const float* __restrict__ qs,
                                                     const float* __restrict__ ks,
                                                     const float* __restrict__ wb,
                                                     const float* __restrict__ nb,
                                                     const float* __restrict__ Mc,
                                                     float* __restrict__ cb) {
    const int bh = blockIdx.x;
    const int r = blockIdx.y;
    const int s0 = r * 64;
    __shared__ float Qs[64][65];
    __shared__ float Kt[64][65];
    __shared__ float At[64][65];
    __shared__ float Wt[64 * 16];
    __shared__ float Pt[64 * 16];
    __shared__ float Lg[64][17];
    const int t = threadIdx.x;
    const int am = t >> 4, an = t & 15;
    const float* qbase = qs + ((size_t)bh * SL + s0) * DH;
    const float* kbase = ks + ((size_t)bh * SL + s0) * DH;
#pragma unroll
    for (int p = 0; p < 4; ++p) {
        const int idx = (p * 256 + t) * 4;
        const int row = idx >> 6, col = idx & 63;
        const float4 qv = *(const float4*)&qbase[idx];
        Qs[row][col + 0] = qv.x; Qs[row][col + 1] = qv.y;
        Qs[row][col + 2] = qv.z; Qs[row][col + 3] = qv.w;
        const float4 kv = *(const float4*)&kbase[idx];
        Kt[row][col + 0] = kv.x; Kt[row][col + 1] = kv.y;
        Kt[row][col + 2] = kv.z; Kt[row][col + 3] = kv.w;
    }
    *(float4*)&Wt[t * 4] = *(const float4*)&wb[((size_t)bh * SL + s0) * NG + t * 4];
    *(float4*)&Pt[t * 4] = *(const float4*)&Mc[(size_t)(bh * NCH + r) * 1024 + t * 4];
    __syncthreads();
    float a[4][4] = {};
#pragma unroll 8
    for (int e = 0; e < 64; ++e) {
        float qv[4], kv[4];
#pragma unroll
        for (int j = 0; j < 4; ++j) qv[j] = Qs[am * 4 + j][e];
#pragma unroll
        for (int jj = 0; jj < 4; ++jj) kv[jj] = Kt[an * 4 + jj][e];
#pragma unroll
        for (int j = 0; j < 4; ++j)
#pragma unroll
            for (int jj = 0; jj < 4; ++jj) a[j][jj] += qv[j] * kv[jj];
    }
#pragma unroll
    for (int j = 0; j < 4; ++j)
#pragma unroll
        for (int jj = 0; jj < 4; ++jj) {
            if (an * 4 + jj > am * 4 + j) a[j][jj] = 0.f;
            At[am * 4 + j][an * 4 + jj] = a[j][jj];
        }
    __syncthreads();
    float lg[4] = {0.f, 0.f, 0.f, 0.f};
#pragma unroll 8
    for (int ii = 0; ii < 64; ++ii) {
        const float wv = Wt[ii * 16 + an];
#pragma unroll
        for (int j = 0; j < 4; ++j) lg[j] += At[am * 4 + j][ii] * wv;
    }
#pragma unroll 8
    for (int e = 0; e < 64; ++e) {
        const float pv = Pt[e * 16 + an];
#pragma unroll
        for (int j = 0; j < 4; ++j) lg[j] += Qs[am * 4 + j][e] * pv;
    }
#pragma unroll
    for (int j = 0; j < 4; ++j) Lg[am * 4 + j][an] = lg[j];
    __syncthreads();
    if (t < 64) {
        const int s = s0 + t;
        const float* nbase = nb + (size_t)bh * NG * SL + s;
        float nv[16], l[16];
        float mx = -1e30f;
#pragma unroll
        for (int g = 0; g < 16; ++g) {
            nv[g] = nbase[(size_t)g * SL];
            l[g] = Lg[t][g] / nv[g];
            mx = fmaxf(mx, l[g]);
        }
        float sum = 0.f;
#pragma unroll
        for (int g = 0; g < 16; ++g) { l[g] = expf(l[g] - mx); sum += l[g]; }
        const float inv = 1.f / sum;
#pragma unroll
        for (int g = 0; g < 16; ++g)
            cb[((size_t)bh * SL + s) * NG + g] = l[g] * inv / nv[g];
    }
}

// ---------------------------------------------------------------------------
// out[s,e] = C@U + causal(C W^T)@V  -> ohb (B,S,512) bf16
// ---------------------------------------------------------------------------
__global__ __launch_bounds__(256) void pass2c_kernel(const float* __restrict__ cb,
                                                     const float* __restrict__ wb,
                                                     const float* __restrict__ vs,
                                                     const float* __restrict__ Nc,
                                                     ushort* __restrict__ ohb) {
    const int bh = blockIdx.x;
    const int b = bh >> 3, h = bh & 7;
    const int r = blockIdx.y;
    const int s0 = r * 64;
    __shared__ float Ct[64][17];
    __shared__ float Wt[64][17];
    __shared__ float Vt[64 * 64];
    __shared__ float St[64][65];
    __shared__ float Ut[16 * 64];
    const int t = threadIdx.x;
    const int am = t >> 4, an = t & 15;
    {
        const int idx = t * 4;
        const int row = idx >> 4, g0 = idx & 15;
        const float4 cv = *(const float4*)&cb[((size_t)bh * SL + s0) * NG + idx];
        Ct[row][g0 + 0] = cv.x; Ct[row][g0 + 1] = cv.y;
        Ct[row][g0 + 2] = cv.z; Ct[row][g0 + 3] = cv.w;
        const float4 wv = *(const float4*)&wb[((size_t)bh * SL + s0) * NG + idx];
        Wt[row][g0 + 0] = wv.x; Wt[row][g0 + 1] = wv.y;
        Wt[row][g0 + 2] = wv.z; Wt[row][g0 + 3] = wv.w;
    }
    const float* vbase = vs + ((size_t)bh * SL + s0) * DH;
#pragma unroll
    for (int p = 0; p < 4; ++p) {
        const int idx = (p * 256 + t) * 4;
        *(float4*)&Vt[idx] = *(const float4*)&vbase[idx];
    }
    *(float4*)&Ut[t * 4] = *(const float4*)&Nc[(size_t)(bh * NCH + r) * 1024 + t * 4];
    __syncthreads();
    float sv[4][4] = {};
#pragma unroll
    for (int g = 0; g < 16; ++g) {
        float cv[4], wv[4];
#pragma unroll
        for (int j = 0; j < 4; ++j) cv[j] = Ct[am * 4 + j][g];
#pragma unroll
        for (int jj = 0; jj < 4; ++jj) wv[jj] = Wt[an * 4 + jj][g];
#pragma unroll
        for (int j = 0; j < 4; ++j)
#pragma unroll
            for (int jj = 0; jj < 4; ++jj) sv[j][jj] += cv[j] * wv[jj];
    }
#pragma unroll
    for (int j = 0; j < 4; ++j)
#pragma unroll
        for (int jj = 0; jj < 4; ++jj) {
            if (an * 4 + jj > am * 4 + j) sv[j][jj] = 0.f;
            St[am * 4 + j][an * 4 + jj] = sv[j][jj];
        }
    __syncthreads();
    float acc[4][4] = {};
#pragma unroll
    for (int g = 0; g < 16; ++g) {
        const float4 u = *(const float4*)&Ut[g * 64 + an * 4];
        float cv[4];
#pragma unroll
        for (int j = 0; j < 4; ++j) cv[j] = Ct[am * 4 + j][g];
#pragma unroll
        for (int j = 0; j < 4; ++j) {
            acc[j][0] += cv[j] * u.x; acc[j][1] += cv[j] * u.y;
            acc[j][2] += cv[j] * u.z; acc[j][3] += cv[j] * u.w;
        }
    }
#pragma unroll 8
    for (int ii = 0; ii < 64; ++ii) {
        const float4 vv = *(const float4*)&Vt[ii * 64 + an * 4];
        float st[4];
#pragma unroll
        for (int j = 0; j < 4; ++j) st[j] = St[am * 4 + j][ii];
#pragma unroll
        for (int j = 0; j < 4; ++j) {
            acc[j][0] += st[j] * vv.x; acc[j][1] += st[j] * vv.y;
            acc[j][2] += st[j] * vv.z; acc[j][3] += st[j] * vv.w;
        }
    }
#pragma unroll
    for (int j = 0; j < 4; ++j) {
        const int s = s0 + am * 4 + j;
        ushort4 pk;
        pk.x = f2bf(acc[j][0]); pk.y = f2bf(acc[j][1]);
        pk.z = f2bf(acc[j][2]); pk.w = f2bf(acc[j][3]);
        *(ushort4*)&ohb[((size_t)b * SL + s) * 512 + h * DH + an * 4] = pk;
    }
}

// ---------------------------------------------------------------------------
extern "C" void kernel_launch(void* const* d_in, const int* in_sizes, int n_in,
                              void* d_out, int out_size, void* d_ws, size_t ws_size,
                              hipStream_t stream) {
    const float* query   = (const float*)d_in[0];
    const float* key     = (const float*)d_in[1];
    const float* value   = (const float*)d_in[2];
    const float* context = (const float*)d_in[3];
    const float* qp = (const float*)d_in[4];
    const float* kp = (const float*)d_in[5];
    const float* vp = (const float*)d_in[6];
    const float* op = (const float*)d_in[7];
    const float* cp = (const float*)d_in[8];
    float* out = (float*)d_out;
    float* ws = (float*)d_ws;

    // ---- workspace layout (86.1 MB, with verified-lifetime aliasing) ----
    float* qs = ws;                         // 4,194,304 f32
    float* ks = qs + 4194304;               // 4,194,304
    float* vs = ks + 4194304;               // 4,194,304
    float* cs = vs + 4194304;               // 32,768
    float* r5 = cs + 32768;                 // 2,097,152 f32
    float*  wb = r5;                        //   1,048,576 (written AFTER qb dead)
    float*  nb = r5 + 1048576;              //   1,048,576
    ushort* qb = (ushort*)r5;               //   4,194,304 bf16 (dead after qs-gemm)
    float* r6 = r5 + 2097152;               // 2,097,152 f32
    float*  Mc = r6;                        //   1,048,576 (after kb dead)
    float*  cb = r6 + 1048576;              //   1,048,576
    ushort* kb = (ushort*)r6;               //   4,194,304 bf16 (dead after ks-gemm)
    float* r7 = r6 + 2097152;               // 2,097,152 f32
    float*  Nc = r7;                        //   1,048,576 (after vb dead)
    ushort* vb = (ushort*)r7;               //   4,194,304 bf16 (dead after vs-gemm)
    float* r8 = r7 + 2097152;               // 2,097,152 f32
    ushort* ohb = (ushort*)r8;              //   4,194,304 bf16
    float* r9 = r8 + 2097152;               // 524,288 f32: 4 transposed bf16 weights
    ushort* qpT = (ushort*)r9;
    ushort* kpT = qpT + 262144;
    ushort* vpT = kpT + 262144;
    ushort* opT = vpT + 262144;

    dim3 blk(256);
    conv_bf16<<<dim3(4096), blk, 0, stream>>>((const float4*)query, (ushort4*)qb);
    conv_bf16<<<dim3(4096), blk, 0, stream>>>((const float4*)key, (ushort4*)kb);
    conv_bf16<<<dim3(4096), blk, 0, stream>>>((const float4*)value, (ushort4*)vb);
    convT512<<<dim3(16, 16), blk, 0, stream>>>(qp, qpT);
    convT512<<<dim3(16, 16), blk, 0, stream>>>(kp, kpT);
    convT512<<<dim3(16, 16), blk, 0, stream>>>(vp, vpT);
    convT512<<<dim3(16, 16), blk, 0, stream>>>(op, opT);
    gemm_mfma<0><<<dim3(64, 4), blk, 0, stream>>>(qb, qpT, qs, SL);
    gemm_mfma<0><<<dim3(64, 4), blk, 0, stream>>>(kb, kpT, ks, SL);
    gemm_mfma<0><<<dim3(64, 4), blk, 0, stream>>>(vb, vpT, vs, SL);
    gemm512<0><<<dim3(1, 8), blk, 0, stream>>>(context, cp, cs, NG);
    compute_w_kernel<<<dim3(NBH, SL / 128), blk, 0, stream>>>(ks, cs, wb);
    scan_kernel<<<dim3(NBH * NG), blk, 0, stream>>>(wb, nb);
    chunk_sums_kernel<<<dim3(NBH, NCH), blk, 0, stream>>>(ks, wb, vs, Mc, Nc);
    scan_chunks_kernel<<<dim3(NBH * 2), blk, 0, stream>>>(Mc, Nc);
    pass1c_kernel<<<dim3(NBH, NCH), blk, 0, stream>>>(qs, ks, wb, nb, Mc, cb);
    pass2c_kernel<<<dim3(NBH, NCH), blk, 0, stream>>>(cb, wb, vs, Nc, ohb);
    gemm_mfma<1><<<dim3(64, 4), blk, 0, stream>>>(ohb, opT, out, 1);
}

// Round 7
// 171.980 us; speedup vs baseline: 4.5439x; 1.2076x over previous
//
#include <hip/hip_runtime.h>
#include <hip/hip_bf16.h>

#define NB 4
#define SL 2048
#define NG 16
#define NH 8
#define DH 64
#define NBH (NB * NH)
#define NCH (SL / 64)  // 32 chunks of 64

typedef __attribute__((ext_vector_type(8))) short bh8;
typedef __attribute__((ext_vector_type(4))) float fx4;

__device__ __forceinline__ ushort f2bf(float x) {
    union { float f; unsigned u; } v; v.f = x;
    const unsigned r = v.u + 0x7fffu + ((v.u >> 16) & 1u);  // RNE
    return (ushort)(r >> 16);
}

// ---------------------------------------------------------------------------
// f32 -> bf16 for q,k,v in one launch.  grid (4096, 3).
// ---------------------------------------------------------------------------
__global__ __launch_bounds__(256) void conv_bf16_3(const float4* __restrict__ q,
                                                   const float4* __restrict__ k,
                                                   const float4* __restrict__ v,
                                                   ushort4* __restrict__ qo,
                                                   ushort4* __restrict__ ko,
                                                   ushort4* __restrict__ vo) {
    const int i = blockIdx.x * 256 + threadIdx.x;
    const float4* in = (blockIdx.y == 0) ? q : (blockIdx.y == 1) ? k : v;
    ushort4* outp = (blockIdx.y == 0) ? qo : (blockIdx.y == 1) ? ko : vo;
    const float4 x = in[i];
    ushort4 o;
    o.x = f2bf(x.x); o.y = f2bf(x.y); o.z = f2bf(x.z); o.w = f2bf(x.w);
    outp[i] = o;
}

// ---------------------------------------------------------------------------
// Four weights (512x512 f32 [e][d]) -> bf16 transposed [d][e].  grid (16,16,4)
// ---------------------------------------------------------------------------
__global__ __launch_bounds__(256) void convT512_4(const float* __restrict__ w0,
                                                  const float* __restrict__ w1,
                                                  const float* __restrict__ w2,
                                                  const float* __restrict__ w3,
                                                  ushort* __restrict__ o0,
                                                  ushort* __restrict__ o1,
                                                  ushort* __restrict__ o2,
                                                  ushort* __restrict__ o3) {
    const int z = blockIdx.z;
    const float* W = (z == 0) ? w0 : (z == 1) ? w1 : (z == 2) ? w2 : w3;
    ushort* WT = (z == 0) ? o0 : (z == 1) ? o1 : (z == 2) ? o2 : o3;
    __shared__ float tile[32][33];
    const int bx = blockIdx.x * 32, by = blockIdx.y * 32;
    const int tx = threadIdx.x & 31, ty = threadIdx.x >> 5;
#pragma unroll
    for (int p = 0; p < 4; ++p)
        tile[ty + p * 8][tx] = W[(size_t)(by + ty + p * 8) * 512 + bx + tx];
    __syncthreads();
#pragma unroll
    for (int p = 0; p < 4; ++p)
        WT[(size_t)(bx + ty + p * 8) * 512 + by + tx] = f2bf(tile[tx][ty + p * 8]);
}

// ---------------------------------------------------------------------------
// MFMA GEMM body: A (Mx512 bf16) @ BT^T (BT 512x512 bf16 [n][k]) -> f32 out.
// 128x128 tile, BK=32, double-buffered LDS, ONE barrier per K-step.
// MODE 0: heads layout; MODE 1: plain row-major.
// ---------------------------------------------------------------------------
template <int MODE>
__device__ __forceinline__ void gemm_body(const ushort* __restrict__ A,
                                          const ushort* __restrict__ BT,
                                          float* __restrict__ out, int n) {
    __shared__ __align__(16) ushort As[2][128 * 32];
    __shared__ __align__(16) ushort Bs[2][128 * 32];
    const int t = threadIdx.x;
    const int lane = t & 63, w = t >> 6;
    const int bm = blockIdx.x * 128, bn = blockIdx.y * 128;
    const int e0 = w * 1024 + lane * 8;
    const int e1 = e0 + 512;
    const int r0 = e0 >> 5, c0 = e0 & 31;
    const int r1 = e1 >> 5, c1 = e1 & 31;
    const size_t a0 = (size_t)(bm + r0) * 512 + c0;
    const size_t a1 = (size_t)(bm + r1) * 512 + c1;
    const size_t b0 = (size_t)(bn + r0) * 512 + c0;
    const size_t b1 = (size_t)(bn + r1) * 512 + c1;
    const int wr = w >> 1, wc = w & 1;
    const int fr = lane & 15, kg = lane >> 4;
    const int aoff = (wr * 64 + fr) * 32 + kg * 8;
    const int boff = (wc * 64 + fr) * 32 + kg * 8;
    fx4 acc[4][4] = {};

#define STAGE_TILE(buf, kk)                                                        \
    do {                                                                           \
        __builtin_amdgcn_global_load_lds(                                          \
            (const __attribute__((address_space(1))) void*)(A + a0 + (kk)),        \
            (__attribute__((address_space(3))) void*)&As[buf][w * 1024], 16, 0, 0);\
        __builtin_amdgcn_global_load_lds(                                          \
            (const __attribute__((address_space(1))) void*)(A + a1 + (kk)),        \
            (__attribute__((address_space(3))) void*)&As[buf][w * 1024 + 512], 16, 0, 0);\
        __builtin_amdgcn_global_load_lds(                                          \
            (const __attribute__((address_space(1))) void*)(BT + b0 + (kk)),       \
            (__attribute__((address_space(3))) void*)&Bs[buf][w * 1024], 16, 0, 0);\
        __builtin_amdgcn_global_load_lds(                                          \
            (const __attribute__((address_space(1))) void*)(BT + b1 + (kk)),       \
            (__attribute__((address_space(3))) void*)&Bs[buf][w * 1024 + 512], 16, 0, 0);\
    } while (0)

    STAGE_TILE(0, 0);
    __syncthreads();
    int cur = 0;
    for (int k0 = 0; k0 < 512; k0 += 32) {
        if (k0 + 32 < 512) STAGE_TILE(cur ^ 1, k0 + 32);  // prefetch overlaps MFMA
        bh8 af[4], bf[4];
#pragma unroll
        for (int m = 0; m < 4; ++m) af[m] = *(const bh8*)&As[cur][aoff + m * 512];
#pragma unroll
        for (int nn = 0; nn < 4; ++nn) bf[nn] = *(const bh8*)&Bs[cur][boff + nn * 512];
#pragma unroll
        for (int m = 0; m < 4; ++m)
#pragma unroll
            for (int nn = 0; nn < 4; ++nn)
                acc[m][nn] = __builtin_amdgcn_mfma_f32_16x16x32_bf16(
                    af[m], bf[nn], acc[m][nn], 0, 0, 0);
        __syncthreads();  // drains prefetch loads too (issued a full MFMA phase ago)
        cur ^= 1;
    }
#undef STAGE_TILE
#pragma unroll
    for (int m = 0; m < 4; ++m)
#pragma unroll
        for (int nn = 0; nn < 4; ++nn)
#pragma unroll
            for (int j = 0; j < 4; ++j) {
                const int r = bm + wr * 64 + m * 16 + kg * 4 + j;
                const int cc = bn + wc * 64 + nn * 16 + fr;
                if (MODE == 0) {
                    const int b = r / n, i = r % n;
                    out[(((size_t)(b * NH) + (cc >> 6)) * n + i) * DH + (cc & 63)] =
                        acc[m][nn][j];
                } else {
                    out[(size_t)r * 512 + cc] = acc[m][nn][j];
                }
            }
}

// Q/K/V projections batched: grid (64, 4, 3) = 768 blocks -> 3 blocks/CU.
__global__ __launch_bounds__(256, 3) void gemm_qkv_kernel(
    const ushort* __restrict__ qb, const ushort* __restrict__ kb,
    const ushort* __restrict__ vb, const ushort* __restrict__ qpT,
    const ushort* __restrict__ kpT, const ushort* __restrict__ vpT,
    float* __restrict__ qs, float* __restrict__ ks, float* __restrict__ vs) {
    const int z = blockIdx.z;
    const ushort* A = (z == 0) ? qb : (z == 1) ? kb : vb;
    const ushort* BT = (z == 0) ? qpT : (z == 1) ? kpT : vpT;
    float* out = (z == 0) ? qs : (z == 1) ? ks : vs;
    gemm_body<0>(A, BT, out, SL);
}

// Output projection: grid (64, 4).
__global__ __launch_bounds__(256) void gemm_out_kernel(const ushort* __restrict__ A,
                                                       const ushort* __restrict__ BT,
                                                       float* __restrict__ out) {
    gemm_body<1>(A, BT, out, 1);
}

// ---------------------------------------------------------------------------
// f32 GEMM for the tiny context projection (64 rows).
// ---------------------------------------------------------------------------
template <int MODE>
__global__ __launch_bounds__(256) void gemm512(const float* __restrict__ X,
                                               const float* __restrict__ Wm,
                                               float* __restrict__ out, int n) {
    __shared__ float As[16][65];
    __shared__ float Bs[16][64];
    const int t = threadIdx.x;
    const int rm = blockIdx.x * 64;
    const int cn = blockIdx.y * 64;
    const int tm = t >> 4, tn = t & 15;
    const int arow = t >> 2, ak = (t & 3) << 2;
    const int bk = t >> 4, bc = (t & 15) << 2;
    float acc[4][4] = {};
    for (int k0 = 0; k0 < 512; k0 += 16) {
        float4 av = *(const float4*)&X[(size_t)(rm + arow) * 512 + k0 + ak];
        float4 bv = *(const float4*)&Wm[(size_t)(k0 + bk) * 512 + cn + bc];
        __syncthreads();
        As[ak + 0][arow] = av.x;
        As[ak + 1][arow] = av.y;
        As[ak + 2][arow] = av.z;
        As[ak + 3][arow] = av.w;
        *(float4*)&Bs[bk][bc] = bv;
        __syncthreads();
#pragma unroll
        for (int kk = 0; kk < 16; ++kk) {
            float a0 = As[kk][tm * 4 + 0], a1 = As[kk][tm * 4 + 1];
            float a2 = As[kk][tm * 4 + 2], a3 = As[kk][tm * 4 + 3];
            float4 b = *(const float4*)&Bs[kk][tn * 4];
            acc[0][0] += a0 * b.x; acc[0][1] += a0 * b.y; acc[0][2] += a0 * b.z; acc[0][3] += a0 * b.w;
            acc[1][0] += a1 * b.x; acc[1][1] += a1 * b.y; acc[1][2] += a1 * b.z; acc[1][3] += a1 * b.w;
            acc[2][0] += a2 * b.x; acc[2][1] += a2 * b.y; acc[2][2] += a2 * b.z; acc[2][3] += a2 * b.w;
            acc[3][0] += a3 * b.x; acc[3][1] += a3 * b.y; acc[3][2] += a3 * b.z; acc[3][3] += a3 * b.w;
        }
    }
#pragma unroll
    for (int j = 0; j < 4; ++j) {
        const int r = rm + tm * 4 + j;
#pragma unroll
        for (int jj = 0; jj < 4; ++jj) {
            const int cc = cn + tn * 4 + jj;
            if (MODE == 0) {
                const int b = r / n, i = r % n;
                out[(((size_t)(b * NH) + (cc >> 6)) * n + i) * DH + (cc & 63)] = acc[j][jj];
            } else {
                out[(size_t)r * 512 + cc] = acc[j][jj];
            }
        }
    }
}

// ---------------------------------------------------------------------------
// w[bh,i,g] = exp(cs[bh,g,:] . ks[bh,i,:])   stored (bh, i, g)
// ---------------------------------------------------------------------------
__global__ __launch_bounds__(256) void compute_w_kernel(const float* __restrict__ ks,
                                                        const float* __restrict__ cs,
                                                        float* __restrict__ wb) {
    const int bh = blockIdx.x;
    const int i0 = blockIdx.y * 128;
    __shared__ float Ks[128 * 64];
    __shared__ float Cs[16][65];
    const int t = threadIdx.x;
    const float* kbase = ks + ((size_t)bh * SL + i0) * DH;
#pragma unroll
    for (int p = 0; p < 8; ++p) {
        const int idx = (p * 256 + t) * 4;
        *(float4*)&Ks[idx] = *(const float4*)&kbase[idx];
    }
    const float* cbase = cs + (size_t)bh * NG * DH;
#pragma unroll
    for (int p = 0; p < 4; ++p) {
        const int idx = p * 256 + t;
        Cs[idx >> 6][idx & 63] = cbase[idx];
    }
    __syncthreads();
    const int g = t & 15;
    const int isub = t >> 4;
    for (int rr = 0; rr < 8; ++rr) {
        const int i = isub + rr * 16;
        float d = 0.f;
#pragma unroll 8
        for (int e = 0; e < 64; ++e) d += Ks[i * 64 + e] * Cs[g][e];
        wb[((size_t)bh * SL + i0 + i) * NG + g] = expf(d);
    }
}

// ---------------------------------------------------------------------------
// n[bhg, s] = inclusive cumsum over s of w[bh, s, g].
// ---------------------------------------------------------------------------
__global__ __launch_bounds__(256) void scan_kernel(const float* __restrict__ wb,
                                                   float* __restrict__ nb) {
    const int bhg = blockIdx.x;
    const int bh = bhg >> 4, g = bhg & 15;
    __shared__ float sw[2048];
    __shared__ float sp[256];
    const int t = threadIdx.x;
    for (int p = 0; p < 8; ++p) {
        const int s = p * 256 + t;
        sw[s] = wb[((size_t)bh * SL + s) * NG + g];
    }
    __syncthreads();
    float loc[8];
    float run = 0.f;
#pragma unroll
    for (int j = 0; j < 8; ++j) { run += sw[t * 8 + j]; loc[j] = run; }
    sp[t] = run;
    __syncthreads();
    for (int off = 1; off < 256; off <<= 1) {
        const float v = sp[t];
        const float add = (t >= off) ? sp[t - off] : 0.f;
        __syncthreads();
        sp[t] = v + add;
        __syncthreads();
    }
    const float offs = (t > 0) ? sp[t - 1] : 0.f;
#pragma unroll
    for (int j = 0; j < 8; ++j)
        nb[(size_t)bhg * SL + t * 8 + j] = offs + loc[j];
}

// ---------------------------------------------------------------------------
// per-chunk state sums.  M_c[e,g] (64x16), N_c[g,e] (16x64)
// ---------------------------------------------------------------------------
__global__ __launch_bounds__(256) void chunk_sums_kernel(const float* __restrict__ ks,
                                                         const float* __restrict__ wb,
                                                         const float* __restrict__ vs,
                                                         float* __restrict__ Mc,
                                                         float* __restrict__ Nc) {
    const int bh = blockIdx.x, c = blockIdx.y;
    __shared__ float Ks[64 * 64];
    __shared__ float Vs[64 * 64];
    __shared__ float Ws[64 * 16];
    const int t = threadIdx.x;
    const float* kbase = ks + ((size_t)bh * SL + c * 64) * DH;
    const float* vbase = vs + ((size_t)bh * SL + c * 64) * DH;
#pragma unroll
    for (int p = 0; p < 4; ++p) {
        const int idx = (p * 256 + t) * 4;
        *(float4*)&Ks[idx] = *(const float4*)&kbase[idx];
        *(float4*)&Vs[idx] = *(const float4*)&vbase[idx];
    }
    *(float4*)&Ws[t * 4] = *(const float4*)&wb[((size_t)bh * SL + c * 64) * NG + t * 4];
    __syncthreads();
    const int e = t >> 2, g0 = (t & 3) * 4;
    float m0 = 0.f, m1 = 0.f, m2 = 0.f, m3 = 0.f;
#pragma unroll 8
    for (int i = 0; i < 64; ++i) {
        const float kv = Ks[i * 64 + e];
        const float4 w = *(const float4*)&Ws[i * 16 + g0];
        m0 += kv * w.x; m1 += kv * w.y; m2 += kv * w.z; m3 += kv * w.w;
    }
    const int g2 = t >> 4, e2 = (t & 15) * 4;
    float n0 = 0.f, n1 = 0.f, n2 = 0.f, n3 = 0.f;
#pragma unroll 8
    for (int i = 0; i < 64; ++i) {
        const float wv = Ws[i * 16 + g2];
        const float4 vv = *(const float4*)&Vs[i * 64 + e2];
        n0 += wv * vv.x; n1 += wv * vv.y; n2 += wv * vv.z; n3 += wv * vv.w;
    }
    float* mo = Mc + ((size_t)(bh * NCH + c) * 64 + e) * 16 + g0;
    mo[0] = m0; mo[1] = m1; mo[2] = m2; mo[3] = m3;
    float* no = Nc + ((size_t)(bh * NCH + c) * 16 + g2) * 64 + e2;
    no[0] = n0; no[1] = n1; no[2] = n2; no[3] = n3;
}

// ---------------------------------------------------------------------------
// in-place exclusive scan over chunks of the 1024-elem states.
// ---------------------------------------------------------------------------
__global__ __launch_bounds__(256) void scan_chunks_kernel(float* __restrict__ Mc,
                                                          float* __restrict__ Nc) {
    const int bh = blockIdx.x >> 1;
    float* base = ((blockIdx.x & 1) ? Nc : Mc) + (size_t)bh * NCH * 1024;
    const int t = threadIdx.x;
    float4 run = make_float4(0.f, 0.f, 0.f, 0.f);
    for (int c = 0; c < NCH; ++c) {
        float4* p = (float4*)&base[c * 1024 + t * 4];
        const float4 v = *p;
        *p = run;
        run.x += v.x; run.y += v.y; run.z += v.z; run.w += v.w;
    }
}

// ---------------------------------------------------------------------------
// logits[s,g] = Q@P + causal(Q K^T)@W, /n, softmax over g, c = p/(sum*n)
// ---------------------------------------------------------------------------
__global__ __launch_bounds__(256) void pass1c_kernel(const float* __restrict__ qs,
                                                     const float* __restrict__ ks,
                                                     const float* __restrict__ wb,
                                                     const float* __restrict__ nb,
                                                     const float* __restrict__ Mc,
                                                     float* __restrict__ cb) {
    const int bh = blockIdx.x;
    const int r = blockIdx.y;
    const int s0 = r * 64;
    __shared__ float Qs[64][65];
    __shared__ float Kt[64][65];
    __shared__ float At[64][65];
    __shared__ float Wt[64 * 16];
    __shared__ float Pt[64 * 16];
    __shared__ float Lg[64][17];
    const int t = threadIdx.x;
    const int am = t >> 4, an = t & 15;
    const float* qbase = qs + ((size_t)bh * SL + s0) * DH;
    const float* kbase = ks + ((size_t)bh * SL + s0) * DH;
#pragma unroll
    for (int p = 0; p < 4; ++p) {
        const int idx = (p * 256 + t) * 4;
        const int row = idx >> 6, col = idx & 63;
        const float4 qv = *(const float4*)&qbase[idx];
        Qs[row][col + 0] = qv.x; Qs[row][col + 1] = qv.y;
        Qs[row][col + 2] = qv.z; Qs[row][col + 3] = qv.w;
        const float4 kv = *(const float4*)&kbase[idx];
        Kt[row][col + 0] = kv.x; Kt[row][col + 1] = kv.y;
        Kt[row][col + 2] = kv.z; Kt[row][col + 3] = kv.w;
    }
    *(float4*)&Wt[t * 4] = *(const float4*)&wb[((size_t)bh * SL + s0) * NG + t * 4];
    *(float4*)&Pt[t * 4] = *(const float4*)&Mc[(size_t)(bh * NCH + r) * 1024 + t * 4];
    __syncthreads();
    float a[4][4] = {};
#pragma unroll 8
    for (int e = 0; e < 64; ++e) {
        float qv[4], kv[4];
#pragma unroll
        for (int j = 0; j < 4; ++j) qv[j] = Qs[am * 4 + j][e];
#pragma unroll
        for (int jj = 0; jj < 4; ++jj) kv[jj] = Kt[an * 4 + jj][e];
#pragma unroll
        for (int j = 0; j < 4; ++j)
#pragma unroll
            for (int jj = 0; jj < 4; ++jj) a[j][jj] += qv[j] * kv[jj];
    }
#pragma unroll
    for (int j = 0; j < 4; ++j)
#pragma unroll
        for (int jj = 0; jj < 4; ++jj) {
            if (an * 4 + jj > am * 4 + j) a[j][jj] = 0.f;
            At[am * 4 + j][an * 4 + jj] = a[j][jj];
        }
    __syncthreads();
    float lg[4] = {0.f, 0.f, 0.f, 0.f};
#pragma unroll 8
    for (int ii = 0; ii < 64; ++ii) {
        const float wv = Wt[ii * 16 + an];
#pragma unroll
        for (int j = 0; j < 4; ++j) lg[j] += At[am * 4 + j][ii] * wv;
    }
#pragma unroll 8
    for (int e = 0; e < 64; ++e) {
        const float pv = Pt[e * 16 + an];
#pragma unroll
        for (int j = 0; j < 4; ++j) lg[j] += Qs[am * 4 + j][e] * pv;
    }
#pragma unroll
    for (int j = 0; j < 4; ++j) Lg[am * 4 + j][an] = lg[j];
    __syncthreads();
    if (t < 64) {
        const int s = s0 + t;
        const float* nbase = nb + (size_t)bh * NG * SL + s;
        float nv[16], l[16];
        float mx = -1e30f;
#pragma unroll
        for (int g = 0; g < 16; ++g) {
            nv[g] = nbase[(size_t)g * SL];
            l[g] = Lg[t][g] / nv[g];
            mx = fmaxf(mx, l[g]);
        }
        float sum = 0.f;
#pragma unroll
        for (int g = 0; g < 16; ++g) { l[g] = expf(l[g] - mx); sum += l[g]; }
        const float inv = 1.f / sum;
#pragma unroll
        for (int g = 0; g < 16; ++g)
            cb[((size_t)bh * SL + s) * NG + g] = l[g] * inv / nv[g];
    }
}

// ---------------------------------------------------------------------------
// out[s,e] = C@U + causal(C W^T)@V  -> ohb (B,S,512) bf16
// ---------------------------------------------------------------------------
__global__ __launch_bounds__(256) void pass2c_kernel(const float* __restrict__ cb,
                                                     const float* __restrict__ wb,
                                                     const float* __restrict__ vs,
                                                     const float* __restrict__ Nc,
                                                     ushort* __restrict__ ohb) {
    const int bh = blockIdx.x;
    const int b = bh >> 3, h = bh & 7;
    const int r = blockIdx.y;
    const int s0 = r * 64;
    __shared__ float Ct[64][17];
    __shared__ float Wt[64][17];
    __shared__ float Vt[64 * 64];
    __shared__ float St[64][65];
    __shared__ float Ut[16 * 64];
    const int t = threadIdx.x;
    const int am = t >> 4, an = t & 15;
    {
        const int idx = t * 4;
        const int row = idx >> 4, g0 = idx & 15;
        const float4 cv = *(const float4*)&cb[((size_t)bh * SL + s0) * NG + idx];
        Ct[row][g0 + 0] = cv.x; Ct[row][g0 + 1] = cv.y;
        Ct[row][g0 + 2] = cv.z; Ct[row][g0 + 3] = cv.w;
        const float4 wv = *(const float4*)&wb[((size_t)bh * SL + s0) * NG + idx];
        Wt[row][g0 + 0] = wv.x; Wt[row][g0 + 1] = wv.y;
        Wt[row][g0 + 2] = wv.z; Wt[row][g0 + 3] = wv.w;
    }
    const float* vbase = vs + ((size_t)bh * SL + s0) * DH;
#pragma unroll
    for (int p = 0; p < 4; ++p) {
        const int idx = (p * 256 + t) * 4;
        *(float4*)&Vt[idx] = *(const float4*)&vbase[idx];
    }
    *(float4*)&Ut[t * 4] = *(const float4*)&Nc[(size_t)(bh * NCH + r) * 1024 + t * 4];
    __syncthreads();
    float sv[4][4] = {};
#pragma unroll
    for (int g = 0; g < 16; ++g) {
        float cv[4], wv[4];
#pragma unroll
        for (int j = 0; j < 4; ++j) cv[j] = Ct[am * 4 + j][g];
#pragma unroll
        for (int jj = 0; jj < 4; ++jj) wv[jj] = Wt[an * 4 + jj][g];
#pragma unroll
        for (int j = 0; j < 4; ++j)
#pragma unroll
            for (int jj = 0; jj < 4; ++jj) sv[j][jj] += cv[j] * wv[jj];
    }
#pragma unroll
    for (int j = 0; j < 4; ++j)
#pragma unroll
        for (int jj = 0; jj < 4; ++jj) {
            if (an * 4 + jj > am * 4 + j) sv[j][jj] = 0.f;
            St[am * 4 + j][an * 4 + jj] = sv[j][jj];
        }
    __syncthreads();
    float acc[4][4] = {};
#pragma unroll
    for (int g = 0; g < 16; ++g) {
        const float4 u = *(const float4*)&Ut[g * 64 + an * 4];
        float cv[4];
#pragma unroll
        for (int j = 0; j < 4; ++j) cv[j] = Ct[am * 4 + j][g];
#pragma unroll
        for (int j = 0; j < 4; ++j) {
            acc[j][0] += cv[j] * u.x; acc[j][1] += cv[j] * u.y;
            acc[j][2] += cv[j] * u.z; acc[j][3] += cv[j] * u.w;
        }
    }
#pragma unroll 8
    for (int ii = 0; ii < 64; ++ii) {
        const float4 vv = *(const float4*)&Vt[ii * 64 + an * 4];
        float st[4];
#pragma unroll
        for (int j = 0; j < 4; ++j) st[j] = St[am * 4 + j][ii];
#pragma unroll
        for (int j = 0; j < 4; ++j) {
            acc[j][0] += st[j] * vv.x; acc[j][1] += st[j] * vv.y;
            acc[j][2] += st[j] * vv.z; acc[j][3] += st[j] * vv.w;
        }
    }
#pragma unroll
    for (int j = 0; j < 4; ++j) {
        const int s = s0 + am * 4 + j;
        ushort4 pk;
        pk.x = f2bf(acc[j][0]); pk.y = f2bf(acc[j][1]);
        pk.z = f2bf(acc[j][2]); pk.w = f2bf(acc[j][3]);
        *(ushort4*)&ohb[((size_t)b * SL + s) * 512 + h * DH + an * 4] = pk;
    }
}

// ---------------------------------------------------------------------------
extern "C" void kernel_launch(void* const* d_in, const int* in_sizes, int n_in,
                              void* d_out, int out_size, void* d_ws, size_t ws_size,
                              hipStream_t stream) {
    const float* query   = (const float*)d_in[0];
    const float* key     = (const float*)d_in[1];
    const float* value   = (const float*)d_in[2];
    const float* context = (const float*)d_in[3];
    const float* qp = (const float*)d_in[4];
    const float* kp = (const float*)d_in[5];
    const float* vp = (const float*)d_in[6];
    const float* op = (const float*)d_in[7];
    const float* cp = (const float*)d_in[8];
    float* out = (float*)d_out;
    float* ws = (float*)d_ws;

    // ---- workspace layout (86.1 MB, with verified-lifetime aliasing) ----
    float* qs = ws;                         // 4,194,304 f32
    float* ks = qs + 4194304;               // 4,194,304
    float* vs = ks + 4194304;               // 4,194,304
    float* cs = vs + 4194304;               // 32,768
    float* r5 = cs + 32768;                 // 2,097,152 f32
    float*  wb = r5;                        //   1,048,576 (written AFTER qb dead)
    float*  nb = r5 + 1048576;              //   1,048,576
    ushort* qb = (ushort*)r5;               //   4,194,304 bf16 (dead after qs-gemm)
    float* r6 = r5 + 2097152;               // 2,097,152 f32
    float*  Mc = r6;                        //   1,048,576 (after kb dead)
    float*  cb = r6 + 1048576;              //   1,048,576
    ushort* kb = (ushort*)r6;               //   4,194,304 bf16 (dead after ks-gemm)
    float* r7 = r6 + 2097152;               // 2,097,152 f32
    float*  Nc = r7;                        //   1,048,576 (after vb dead)
    ushort* vb = (ushort*)r7;               //   4,194,304 bf16 (dead after vs-gemm)
    float* r8 = r7 + 2097152;               // 2,097,152 f32
    ushort* ohb = (ushort*)r8;              //   4,194,304 bf16
    float* r9 = r8 + 2097152;               // 524,288 f32: 4 transposed bf16 weights
    ushort* qpT = (ushort*)r9;
    ushort* kpT = qpT + 262144;
    ushort* vpT = kpT + 262144;
    ushort* opT = vpT + 262144;

    dim3 blk(256);
    conv_bf16_3<<<dim3(4096, 3), blk, 0, stream>>>(
        (const float4*)query, (const float4*)key, (const float4*)value,
        (ushort4*)qb, (ushort4*)kb, (ushort4*)vb);
    convT512_4<<<dim3(16, 16, 4), blk, 0, stream>>>(qp, kp, vp, op, qpT, kpT, vpT, opT);
    gemm_qkv_kernel<<<dim3(64, 4, 3), blk, 0, stream>>>(qb, kb, vb, qpT, kpT, vpT,
                                                        qs, ks, vs);
    gemm512<0><<<dim3(1, 8), blk, 0, stream>>>(context, cp, cs, NG);
    compute_w_kernel<<<dim3(NBH, SL / 128), blk, 0, stream>>>(ks, cs, wb);
    scan_kernel<<<dim3(NBH * NG), blk, 0, stream>>>(wb, nb);
    chunk_sums_kernel<<<dim3(NBH, NCH), blk, 0, stream>>>(ks, wb, vs, Mc, Nc);
    scan_chunks_kernel<<<dim3(NBH * 2), blk, 0, stream>>>(Mc, Nc);
    pass1c_kernel<<<dim3(NBH, NCH), blk, 0, stream>>>(qs, ks, wb, nb, Mc, cb);
    pass2c_kernel<<<dim3(NBH, NCH), blk, 0, stream>>>(cb, wb, vs, Nc, ohb);
    gemm_out_kernel<<<dim3(64, 4), blk, 0, stream>>>(ohb, opT, out);
}

// Round 8
// 166.970 us; speedup vs baseline: 4.6802x; 1.0300x over previous
//
#include <hip/hip_runtime.h>
#include <hip/hip_bf16.h>

#define NB 4
#define SL 2048
#define NG 16
#define NH 8
#define DH 64
#define NBH (NB * NH)
#define NCH (SL / 64)  // 32 chunks of 64

typedef __attribute__((ext_vector_type(8))) short bh8;
typedef __attribute__((ext_vector_type(4))) float fx4;

__device__ __forceinline__ ushort f2bf(float x) {
    union { float f; unsigned u; } v; v.f = x;
    const unsigned r = v.u + 0x7fffu + ((v.u >> 16) & 1u);  // RNE
    return (ushort)(r >> 16);
}
__device__ __forceinline__ float b2f(ushort u) {
    union { unsigned u; float f; } v; v.u = ((unsigned)u) << 16;
    return v.f;
}

// ---------------------------------------------------------------------------
// f32 -> bf16 for q,k,v in one launch.  grid (4096, 3).
// ---------------------------------------------------------------------------
__global__ __launch_bounds__(256) void conv_bf16_3(const float4* __restrict__ q,
                                                   const float4* __restrict__ k,
                                                   const float4* __restrict__ v,
                                                   ushort4* __restrict__ qo,
                                                   ushort4* __restrict__ ko,
                                                   ushort4* __restrict__ vo) {
    const int i = blockIdx.x * 256 + threadIdx.x;
    const float4* in = (blockIdx.y == 0) ? q : (blockIdx.y == 1) ? k : v;
    ushort4* outp = (blockIdx.y == 0) ? qo : (blockIdx.y == 1) ? ko : vo;
    const float4 x = in[i];
    ushort4 o;
    o.x = f2bf(x.x); o.y = f2bf(x.y); o.z = f2bf(x.z); o.w = f2bf(x.w);
    outp[i] = o;
}

// ---------------------------------------------------------------------------
// Four weights (512x512 f32 [e][d]) -> bf16 transposed [d][e].  grid (16,16,4)
// ---------------------------------------------------------------------------
__global__ __launch_bounds__(256) void convT512_4(const float* __restrict__ w0,
                                                  const float* __restrict__ w1,
                                                  const float* __restrict__ w2,
                                                  const float* __restrict__ w3,
                                                  ushort* __restrict__ o0,
                                                  ushort* __restrict__ o1,
                                                  ushort* __restrict__ o2,
                                                  ushort* __restrict__ o3) {
    const int z = blockIdx.z;
    const float* W = (z == 0) ? w0 : (z == 1) ? w1 : (z == 2) ? w2 : w3;
    ushort* WT = (z == 0) ? o0 : (z == 1) ? o1 : (z == 2) ? o2 : o3;
    __shared__ float tile[32][33];
    const int bx = blockIdx.x * 32, by = blockIdx.y * 32;
    const int tx = threadIdx.x & 31, ty = threadIdx.x >> 5;
#pragma unroll
    for (int p = 0; p < 4; ++p)
        tile[ty + p * 8][tx] = W[(size_t)(by + ty + p * 8) * 512 + bx + tx];
    __syncthreads();
#pragma unroll
    for (int p = 0; p < 4; ++p)
        WT[(size_t)(bx + ty + p * 8) * 512 + by + tx] = f2bf(tile[tx][ty + p * 8]);
}

// ---------------------------------------------------------------------------
// QKV MFMA GEMM: A (8192x512 bf16) @ BT^T -> bf16 heads layout.
// 128x128 tile, BK=32, double-buffered LDS, one barrier per K-step.
// grid (64, 4, 3) = 768 blocks -> 3 blocks/CU.
// ---------------------------------------------------------------------------
__global__ __launch_bounds__(256, 3) void gemm_qkv_kernel(
    const ushort* __restrict__ qb, const ushort* __restrict__ kb,
    const ushort* __restrict__ vb, const ushort* __restrict__ qpT,
    const ushort* __restrict__ kpT, const ushort* __restrict__ vpT,
    ushort* __restrict__ qsb, ushort* __restrict__ ksb, ushort* __restrict__ vsb) {
    const int z = blockIdx.z;
    const ushort* A = (z == 0) ? qb : (z == 1) ? kb : vb;
    const ushort* BT = (z == 0) ? qpT : (z == 1) ? kpT : vpT;
    ushort* out = (z == 0) ? qsb : (z == 1) ? ksb : vsb;

    __shared__ __align__(16) ushort As[2][128 * 32];
    __shared__ __align__(16) ushort Bs[2][128 * 32];
    const int t = threadIdx.x;
    const int lane = t & 63, w = t >> 6;
    const int bm = blockIdx.x * 128, bn = blockIdx.y * 128;
    const int e0 = w * 1024 + lane * 8;
    const int e1 = e0 + 512;
    const int r0 = e0 >> 5, c0 = e0 & 31;
    const int r1 = e1 >> 5, c1 = e1 & 31;
    const size_t a0 = (size_t)(bm + r0) * 512 + c0;
    const size_t a1 = (size_t)(bm + r1) * 512 + c1;
    const size_t b0 = (size_t)(bn + r0) * 512 + c0;
    const size_t b1 = (size_t)(bn + r1) * 512 + c1;
    const int wr = w >> 1, wc = w & 1;
    const int fr = lane & 15, kg = lane >> 4;
    const int aoff = (wr * 64 + fr) * 32 + kg * 8;
    const int boff = (wc * 64 + fr) * 32 + kg * 8;
    fx4 acc[4][4] = {};

#define STAGE_TILE(buf, kk)                                                        \
    do {                                                                           \
        __builtin_amdgcn_global_load_lds(                                          \
            (const __attribute__((address_space(1))) void*)(A + a0 + (kk)),        \
            (__attribute__((address_space(3))) void*)&As[buf][w * 1024], 16, 0, 0);\
        __builtin_amdgcn_global_load_lds(                                          \
            (const __attribute__((address_space(1))) void*)(A + a1 + (kk)),        \
            (__attribute__((address_space(3))) void*)&As[buf][w * 1024 + 512], 16, 0, 0);\
        __builtin_amdgcn_global_load_lds(                                          \
            (const __attribute__((address_space(1))) void*)(BT + b0 + (kk)),       \
            (__attribute__((address_space(3))) void*)&Bs[buf][w * 1024], 16, 0, 0);\
        __builtin_amdgcn_global_load_lds(                                          \
            (const __attribute__((address_space(1))) void*)(BT + b1 + (kk)),       \
            (__attribute__((address_space(3))) void*)&Bs[buf][w * 1024 + 512], 16, 0, 0);\
    } while (0)

    STAGE_TILE(0, 0);
    __syncthreads();
    int cur = 0;
    for (int k0 = 0; k0 < 512; k0 += 32) {
        if (k0 + 32 < 512) STAGE_TILE(cur ^ 1, k0 + 32);
        bh8 af[4], bf[4];
#pragma unroll
        for (int m = 0; m < 4; ++m) af[m] = *(const bh8*)&As[cur][aoff + m * 512];
#pragma unroll
        for (int nn = 0; nn < 4; ++nn) bf[nn] = *(const bh8*)&Bs[cur][boff + nn * 512];
#pragma unroll
        for (int m = 0; m < 4; ++m)
#pragma unroll
            for (int nn = 0; nn < 4; ++nn)
                acc[m][nn] = __builtin_amdgcn_mfma_f32_16x16x32_bf16(
                    af[m], bf[nn], acc[m][nn], 0, 0, 0);
        __syncthreads();
        cur ^= 1;
    }
#undef STAGE_TILE
#pragma unroll
    for (int m = 0; m < 4; ++m)
#pragma unroll
        for (int nn = 0; nn < 4; ++nn)
#pragma unroll
            for (int j = 0; j < 4; ++j) {
                const int r = bm + wr * 64 + m * 16 + kg * 4 + j;
                const int cc = bn + wc * 64 + nn * 16 + fr;
                const int b = r >> 11, i = r & 2047;  // n == SL == 2048
                out[(((size_t)(b * NH) + (cc >> 6)) * SL + i) * DH + (cc & 63)] =
                    f2bf(acc[m][nn][j]);
            }
}

// ---------------------------------------------------------------------------
// Output MFMA GEMM: ohb (8192x512 bf16) @ opT^T -> f32 plain.
// 128x64 tile -> grid (64, 8) = 512 blocks = 2 blocks/CU.
// ---------------------------------------------------------------------------
__global__ __launch_bounds__(256) void gemm_out_kernel(const ushort* __restrict__ A,
                                                       const ushort* __restrict__ BT,
                                                       float* __restrict__ out) {
    __shared__ __align__(16) ushort As[2][128 * 32];
    __shared__ __align__(16) ushort Bs[2][64 * 32];
    const int t = threadIdx.x;
    const int lane = t & 63, w = t >> 6;
    const int bm = blockIdx.x * 128, bn = blockIdx.y * 64;
    const int e0 = w * 1024 + lane * 8;
    const int e1 = e0 + 512;
    const int r0 = e0 >> 5, c0 = e0 & 31;
    const int r1 = e1 >> 5, c1 = e1 & 31;
    const size_t a0 = (size_t)(bm + r0) * 512 + c0;
    const size_t a1 = (size_t)(bm + r1) * 512 + c1;
    const int eb = w * 512 + lane * 8;
    const int rb = eb >> 5, cbc = eb & 31;
    const size_t b0 = (size_t)(bn + rb) * 512 + cbc;
    const int fr = lane & 15, kg = lane >> 4;
    const int aoff = (w * 32 + fr) * 32 + kg * 8;  // wave w owns rows [w*32, w*32+32)
    const int boff = fr * 32 + kg * 8;
    fx4 acc[2][4] = {};

#define STAGE_O(buf, kk)                                                           \
    do {                                                                           \
        __builtin_amdgcn_global_load_lds(                                          \
            (const __attribute__((address_space(1))) void*)(A + a0 + (kk)),        \
            (__attribute__((address_space(3))) void*)&As[buf][w * 1024], 16, 0, 0);\
        __builtin_amdgcn_global_load_lds(                                          \
            (const __attribute__((address_space(1))) void*)(A + a1 + (kk)),        \
            (__attribute__((address_space(3))) void*)&As[buf][w * 1024 + 512], 16, 0, 0);\
        __builtin_amdgcn_global_load_lds(                                          \
            (const __attribute__((address_space(1))) void*)(BT + b0 + (kk)),       \
            (__attribute__((address_space(3))) void*)&Bs[buf][w * 512], 16, 0, 0); \
    } while (0)

    STAGE_O(0, 0);
    __syncthreads();
    int cur = 0;
    for (int k0 = 0; k0 < 512; k0 += 32) {
        if (k0 + 32 < 512) STAGE_O(cur ^ 1, k0 + 32);
        bh8 af[2], bf[4];
#pragma unroll
        for (int m = 0; m < 2; ++m) af[m] = *(const bh8*)&As[cur][aoff + m * 512];
#pragma unroll
        for (int nn = 0; nn < 4; ++nn) bf[nn] = *(const bh8*)&Bs[cur][boff + nn * 512];
#pragma unroll
        for (int m = 0; m < 2; ++m)
#pragma unroll
            for (int nn = 0; nn < 4; ++nn)
                acc[m][nn] = __builtin_amdgcn_mfma_f32_16x16x32_bf16(
                    af[m], bf[nn], acc[m][nn], 0, 0, 0);
        __syncthreads();
        cur ^= 1;
    }
#undef STAGE_O
#pragma unroll
    for (int m = 0; m < 2; ++m)
#pragma unroll
        for (int nn = 0; nn < 4; ++nn)
#pragma unroll
            for (int j = 0; j < 4; ++j) {
                const int r = bm + w * 32 + m * 16 + kg * 4 + j;
                const int cc = bn + nn * 16 + fr;
                out[(size_t)r * 512 + cc] = acc[m][nn][j];
            }
}

// ---------------------------------------------------------------------------
// f32 GEMM for the tiny context projection (64 rows).  MODE 0 heads layout.
// ---------------------------------------------------------------------------
template <int MODE>
__global__ __launch_bounds__(256) void gemm512(const float* __restrict__ X,
                                               const float* __restrict__ Wm,
                                               float* __restrict__ out, int n) {
    __shared__ float As[16][65];
    __shared__ float Bs[16][64];
    const int t = threadIdx.x;
    const int rm = blockIdx.x * 64;
    const int cn = blockIdx.y * 64;
    const int tm = t >> 4, tn = t & 15;
    const int arow = t >> 2, ak = (t & 3) << 2;
    const int bk = t >> 4, bc = (t & 15) << 2;
    float acc[4][4] = {};
    for (int k0 = 0; k0 < 512; k0 += 16) {
        float4 av = *(const float4*)&X[(size_t)(rm + arow) * 512 + k0 + ak];
        float4 bv = *(const float4*)&Wm[(size_t)(k0 + bk) * 512 + cn + bc];
        __syncthreads();
        As[ak + 0][arow] = av.x;
        As[ak + 1][arow] = av.y;
        As[ak + 2][arow] = av.z;
        As[ak + 3][arow] = av.w;
        *(float4*)&Bs[bk][bc] = bv;
        __syncthreads();
#pragma unroll
        for (int kk = 0; kk < 16; ++kk) {
            float a0 = As[kk][tm * 4 + 0], a1 = As[kk][tm * 4 + 1];
            float a2 = As[kk][tm * 4 + 2], a3 = As[kk][tm * 4 + 3];
            float4 b = *(const float4*)&Bs[kk][tn * 4];
            acc[0][0] += a0 * b.x; acc[0][1] += a0 * b.y; acc[0][2] += a0 * b.z; acc[0][3] += a0 * b.w;
            acc[1][0] += a1 * b.x; acc[1][1] += a1 * b.y; acc[1][2] += a1 * b.z; acc[1][3] += a1 * b.w;
            acc[2][0] += a2 * b.x; acc[2][1] += a2 * b.y; acc[2][2] += a2 * b.z; acc[2][3] += a2 * b.w;
            acc[3][0] += a3 * b.x; acc[3][1] += a3 * b.y; acc[3][2] += a3 * b.z; acc[3][3] += a3 * b.w;
        }
    }
#pragma unroll
    for (int j = 0; j < 4; ++j) {
        const int r = rm + tm * 4 + j;
#pragma unroll
        for (int jj = 0; jj < 4; ++jj) {
            const int cc = cn + tn * 4 + jj;
            if (MODE == 0) {
                const int b = r / n, i = r % n;
                out[(((size_t)(b * NH) + (cc >> 6)) * n + i) * DH + (cc & 63)] = acc[j][jj];
            } else {
                out[(size_t)r * 512 + cc] = acc[j][jj];
            }
        }
    }
}

// ---------------------------------------------------------------------------
// Fused: W = exp(Ks@Cs^T) (written to wb) + per-chunk sums M_c, N_c.
// grid (NBH, NCH).
// ---------------------------------------------------------------------------
__global__ __launch_bounds__(256) void chunk_sums_w_kernel(
    const ushort* __restrict__ ksb, const ushort* __restrict__ vsb,
    const float* __restrict__ cs, float* __restrict__ wb,
    float* __restrict__ Mc, float* __restrict__ Nc) {
    const int bh = blockIdx.x, c = blockIdx.y;
    __shared__ float Ks[64 * 64];
    __shared__ float Vs[64 * 64];
    __shared__ float Ws[64 * 16];
    __shared__ float Cs[16][65];
    const int t = threadIdx.x;
    const ushort* kbase = ksb + ((size_t)bh * SL + c * 64) * DH;
    const ushort* vbase = vsb + ((size_t)bh * SL + c * 64) * DH;
#pragma unroll
    for (int p = 0; p < 2; ++p) {
        const int idx = (p * 256 + t) * 8;
        const bh8 kv = *(const bh8*)&kbase[idx];
        const bh8 vv = *(const bh8*)&vbase[idx];
#pragma unroll
        for (int q = 0; q < 8; ++q) {
            Ks[idx + q] = b2f((ushort)kv[q]);
            Vs[idx + q] = b2f((ushort)vv[q]);
        }
    }
    {
        const int idx = t * 4;  // 1024 floats of Cs
        const float4 cv = *(const float4*)&cs[(size_t)bh * NG * DH + idx];
        const int g = idx >> 6, e = idx & 63;
        Cs[g][e + 0] = cv.x; Cs[g][e + 1] = cv.y; Cs[g][e + 2] = cv.z; Cs[g][e + 3] = cv.w;
    }
    __syncthreads();
    // W: each thread computes 4 outputs (same row i, g0..g0+3)
    {
        const int i = (t * 4) >> 4, g0 = (t * 4) & 15;
        float d0 = 0.f, d1 = 0.f, d2 = 0.f, d3 = 0.f;
#pragma unroll 8
        for (int e = 0; e < 64; ++e) {
            const float kv = Ks[i * 64 + e];
            d0 += kv * Cs[g0 + 0][e];
            d1 += kv * Cs[g0 + 1][e];
            d2 += kv * Cs[g0 + 2][e];
            d3 += kv * Cs[g0 + 3][e];
        }
        float4 wv;
        wv.x = expf(d0); wv.y = expf(d1); wv.z = expf(d2); wv.w = expf(d3);
        *(float4*)&Ws[i * 16 + g0] = wv;
        *(float4*)&wb[((size_t)bh * SL + c * 64 + i) * NG + g0] = wv;
    }
    __syncthreads();
    const int e = t >> 2, g0 = (t & 3) * 4;
    float m0 = 0.f, m1 = 0.f, m2 = 0.f, m3 = 0.f;
#pragma unroll 8
    for (int i = 0; i < 64; ++i) {
        const float kv = Ks[i * 64 + e];
        const float4 w = *(const float4*)&Ws[i * 16 + g0];
        m0 += kv * w.x; m1 += kv * w.y; m2 += kv * w.z; m3 += kv * w.w;
    }
    const int g2 = t >> 4, e2 = (t & 15) * 4;
    float n0 = 0.f, n1 = 0.f, n2 = 0.f, n3 = 0.f;
#pragma unroll 8
    for (int i = 0; i < 64; ++i) {
        const float wv = Ws[i * 16 + g2];
        const float4 vv = *(const float4*)&Vs[i * 64 + e2];
        n0 += wv * vv.x; n1 += wv * vv.y; n2 += wv * vv.z; n3 += wv * vv.w;
    }
    float* mo = Mc + ((size_t)(bh * NCH + c) * 64 + e) * 16 + g0;
    mo[0] = m0; mo[1] = m1; mo[2] = m2; mo[3] = m3;
    float* no = Nc + ((size_t)(bh * NCH + c) * 16 + g2) * 64 + e2;
    no[0] = n0; no[1] = n1; no[2] = n2; no[3] = n3;
}

// ---------------------------------------------------------------------------
// n[bhg, s] = inclusive cumsum over s of w[bh, s, g].
// ---------------------------------------------------------------------------
__global__ __launch_bounds__(256) void scan_kernel(const float* __restrict__ wb,
                                                   float* __restrict__ nb) {
    const int bhg = blockIdx.x;
    const int bh = bhg >> 4, g = bhg & 15;
    __shared__ float sw[2048];
    __shared__ float sp[256];
    const int t = threadIdx.x;
    for (int p = 0; p < 8; ++p) {
        const int s = p * 256 + t;
        sw[s] = wb[((size_t)bh * SL + s) * NG + g];
    }
    __syncthreads();
    float loc[8];
    float run = 0.f;
#pragma unroll
    for (int j = 0; j < 8; ++j) { run += sw[t * 8 + j]; loc[j] = run; }
    sp[t] = run;
    __syncthreads();
    for (int off = 1; off < 256; off <<= 1) {
        const float v = sp[t];
        const float add = (t >= off) ? sp[t - off] : 0.f;
        __syncthreads();
        sp[t] = v + add;
        __syncthreads();
    }
    const float offs = (t > 0) ? sp[t - 1] : 0.f;
#pragma unroll
    for (int j = 0; j < 8; ++j)
        nb[(size_t)bhg * SL + t * 8 + j] = offs + loc[j];
}

// ---------------------------------------------------------------------------
// in-place exclusive scan over chunks; 1-deep prefetch to hide load latency.
// grid (2*NBH): even -> Mc, odd -> Nc.
// ---------------------------------------------------------------------------
__global__ __launch_bounds__(256) void scan_chunks_kernel(float* __restrict__ Mc,
                                                          float* __restrict__ Nc) {
    const int bh = blockIdx.x >> 1;
    float* base = ((blockIdx.x & 1) ? Nc : Mc) + (size_t)bh * NCH * 1024;
    const int t = threadIdx.x;
    float4 run = make_float4(0.f, 0.f, 0.f, 0.f);
    float4 nxt = *(float4*)&base[t * 4];
    for (int c = 0; c < NCH; ++c) {
        const float4 v = nxt;
        if (c + 1 < NCH) nxt = *(float4*)&base[(c + 1) * 1024 + t * 4];
        *(float4*)&base[c * 1024 + t * 4] = run;
        run.x += v.x; run.y += v.y; run.z += v.z; run.w += v.w;
    }
}

// ---------------------------------------------------------------------------
// Fused pass1+pass2:
//   logits = causal(QK^T)@W + Q@P, /n, softmax -> c (LDS only)
//   out    = C@U + causal(C W^T)@V  -> ohb (B,S,512) bf16
// grid (NBH, NCH).  LDS ~65 KB -> 2 blocks/CU.
// ---------------------------------------------------------------------------
__global__ __launch_bounds__(256) void pass12_kernel(
    const ushort* __restrict__ qsb, const ushort* __restrict__ ksb,
    const float* __restrict__ wb, const float* __restrict__ nb,
    const float* __restrict__ Mc, const ushort* __restrict__ vsb,
    const float* __restrict__ Nc, ushort* __restrict__ ohb) {
    const int bh = blockIdx.x;
    const int b = bh >> 3, h = bh & 7;
    const int r = blockIdx.y;
    const int s0 = r * 64;
    __shared__ float S1[64 * 65];   // Qs (row*65+col); later Vt (i*64+e)
    __shared__ float S2[64][65];    // Kt
    __shared__ float S3[64][65];    // At; later St
    __shared__ float Wt[64 * 16];
    __shared__ float S4[64 * 16];   // Pt; later Ut
    __shared__ float Lg[64][17];
    __shared__ float Ct[64][17];
    const int t = threadIdx.x;
    const int am = t >> 4, an = t & 15;
    const ushort* qbase = qsb + ((size_t)bh * SL + s0) * DH;
    const ushort* kbase = ksb + ((size_t)bh * SL + s0) * DH;
#pragma unroll
    for (int p = 0; p < 2; ++p) {
        const int idx = (p * 256 + t) * 8;
        const int row = idx >> 6, col = idx & 63;
        const bh8 qv = *(const bh8*)&qbase[idx];
        const bh8 kv = *(const bh8*)&kbase[idx];
#pragma unroll
        for (int q = 0; q < 8; ++q) {
            S1[row * 65 + col + q] = b2f((ushort)qv[q]);
            S2[row][col + q] = b2f((ushort)kv[q]);
        }
    }
    *(float4*)&Wt[t * 4] = *(const float4*)&wb[((size_t)bh * SL + s0) * NG + t * 4];
    *(float4*)&S4[t * 4] = *(const float4*)&Mc[(size_t)(bh * NCH + r) * 1024 + t * 4];
    __syncthreads();
    // causal QK^T
    float a[4][4] = {};
#pragma unroll 8
    for (int e = 0; e < 64; ++e) {
        float qv[4], kv[4];
#pragma unroll
        for (int j = 0; j < 4; ++j) qv[j] = S1[(am * 4 + j) * 65 + e];
#pragma unroll
        for (int jj = 0; jj < 4; ++jj) kv[jj] = S2[an * 4 + jj][e];
#pragma unroll
        for (int j = 0; j < 4; ++j)
#pragma unroll
            for (int jj = 0; jj < 4; ++jj) a[j][jj] += qv[j] * kv[jj];
    }
#pragma unroll
    for (int j = 0; j < 4; ++j)
#pragma unroll
        for (int jj = 0; jj < 4; ++jj) {
            if (an * 4 + jj > am * 4 + j) a[j][jj] = 0.f;
            S3[am * 4 + j][an * 4 + jj] = a[j][jj];
        }
    __syncthreads();
    float lg[4] = {0.f, 0.f, 0.f, 0.f};
#pragma unroll 8
    for (int ii = 0; ii < 64; ++ii) {
        const float wv = Wt[ii * 16 + an];
#pragma unroll
        for (int j = 0; j < 4; ++j) lg[j] += S3[am * 4 + j][ii] * wv;
    }
#pragma unroll 8
    for (int e = 0; e < 64; ++e) {
        const float pv = S4[e * 16 + an];
#pragma unroll
        for (int j = 0; j < 4; ++j) lg[j] += S1[(am * 4 + j) * 65 + e] * pv;
    }
#pragma unroll
    for (int j = 0; j < 4; ++j) Lg[am * 4 + j][an] = lg[j];
    __syncthreads();   // Lg done; Qs/Pt/At reads all complete
    // stage Vt into S1 (reuse), Ut into S4 (reuse); t<64 does softmax -> Ct
    {
        float* Vt = S1;
        const ushort* vbase = vsb + ((size_t)bh * SL + s0) * DH;
#pragma unroll
        for (int p = 0; p < 2; ++p) {
            const int idx = (p * 256 + t) * 8;
            const bh8 vv = *(const bh8*)&vbase[idx];
#pragma unroll
            for (int q = 0; q < 8; ++q) Vt[idx + q] = b2f((ushort)vv[q]);
        }
        *(float4*)&S4[t * 4] = *(const float4*)&Nc[(size_t)(bh * NCH + r) * 1024 + t * 4];
    }
    if (t < 64) {
        const int s = s0 + t;
        const float* nbase = nb + (size_t)bh * NG * SL + s;
        float nv[16], l[16];
        float mx = -1e30f;
#pragma unroll
        for (int g = 0; g < 16; ++g) {
            nv[g] = nbase[(size_t)g * SL];
            l[g] = Lg[t][g] / nv[g];
            mx = fmaxf(mx, l[g]);
        }
        float sum = 0.f;
#pragma unroll
        for (int g = 0; g < 16; ++g) { l[g] = expf(l[g] - mx); sum += l[g]; }
        const float inv = 1.f / sum;
#pragma unroll
        for (int g = 0; g < 16; ++g) Ct[t][g] = l[g] * inv / nv[g];
    }
    __syncthreads();   // Ct, Vt, Ut ready
    // S = causal(C W^T)
    float sv[4][4] = {};
#pragma unroll
    for (int g = 0; g < 16; ++g) {
        float cv[4], wv[4];
#pragma unroll
        for (int j = 0; j < 4; ++j) cv[j] = Ct[am * 4 + j][g];
#pragma unroll
        for (int jj = 0; jj < 4; ++jj) wv[jj] = Wt[(an * 4 + jj) * 16 + g];
#pragma unroll
        for (int j = 0; j < 4; ++j)
#pragma unroll
            for (int jj = 0; jj < 4; ++jj) sv[j][jj] += cv[j] * wv[jj];
    }
#pragma unroll
    for (int j = 0; j < 4; ++j)
#pragma unroll
        for (int jj = 0; jj < 4; ++jj) {
            if (an * 4 + jj > am * 4 + j) sv[j][jj] = 0.f;
            S3[am * 4 + j][an * 4 + jj] = sv[j][jj];
        }
    __syncthreads();   // St ready
    float acc[4][4] = {};
#pragma unroll
    for (int g = 0; g < 16; ++g) {
        const float4 u = *(const float4*)&S4[g * 64 + an * 4];
        float cv[4];
#pragma unroll
        for (int j = 0; j < 4; ++j) cv[j] = Ct[am * 4 + j][g];
#pragma unroll
        for (int j = 0; j < 4; ++j) {
            acc[j][0] += cv[j] * u.x; acc[j][1] += cv[j] * u.y;
            acc[j][2] += cv[j] * u.z; acc[j][3] += cv[j] * u.w;
        }
    }
#pragma unroll 8
    for (int ii = 0; ii < 64; ++ii) {
        const float4 vv = *(const float4*)&S1[ii * 64 + an * 4];
        float st[4];
#pragma unroll
        for (int j = 0; j < 4; ++j) st[j] = S3[am * 4 + j][ii];
#pragma unroll
        for (int j = 0; j < 4; ++j) {
            acc[j][0] += st[j] * vv.x; acc[j][1] += st[j] * vv.y;
            acc[j][2] += st[j] * vv.z; acc[j][3] += st[j] * vv.w;
        }
    }
#pragma unroll
    for (int j = 0; j < 4; ++j) {
        const int s = s0 + am * 4 + j;
        ushort4 pk;
        pk.x = f2bf(acc[j][0]); pk.y = f2bf(acc[j][1]);
        pk.z = f2bf(acc[j][2]); pk.w = f2bf(acc[j][3]);
        *(ushort4*)&ohb[((size_t)b * SL + s) * 512 + h * DH + an * 4] = pk;
    }
}

// ---------------------------------------------------------------------------
extern "C" void kernel_launch(void* const* d_in, const int* in_sizes, int n_in,
                              void* d_out, int out_size, void* d_ws, size_t ws_size,
                              hipStream_t stream) {
    const float* query   = (const float*)d_in[0];
    const float* key     = (const float*)d_in[1];
    const float* value   = (const float*)d_in[2];
    const float* context = (const float*)d_in[3];
    const float* qp = (const float*)d_in[4];
    const float* kp = (const float*)d_in[5];
    const float* vp = (const float*)d_in[6];
    const float* op = (const float*)d_in[7];
    const float* cp = (const float*)d_in[8];
    float* out = (float*)d_out;

    // ---- workspace layout (~78 MB, no aliasing) ----
    ushort* qb  = (ushort*)d_ws;            // 4,194,304 each
    ushort* kb  = qb + 4194304;
    ushort* vb  = kb + 4194304;
    ushort* qsb = vb + 4194304;
    ushort* ksb = qsb + 4194304;
    ushort* vsb = ksb + 4194304;
    ushort* ohb = vsb + 4194304;
    ushort* qpT = ohb + 4194304;            // 262,144 each
    ushort* kpT = qpT + 262144;
    ushort* vpT = kpT + 262144;
    ushort* opT = vpT + 262144;
    float* fbase = (float*)(opT + 262144);
    float* cs = fbase;                      // 32,768
    float* wb = cs + 32768;                 // 1,048,576 each
    float* nb = wb + 1048576;
    float* Mc = nb + 1048576;
    float* Nc = Mc + 1048576;

    dim3 blk(256);
    conv_bf16_3<<<dim3(4096, 3), blk, 0, stream>>>(
        (const float4*)query, (const float4*)key, (const float4*)value,
        (ushort4*)qb, (ushort4*)kb, (ushort4*)vb);
    convT512_4<<<dim3(16, 16, 4), blk, 0, stream>>>(qp, kp, vp, op, qpT, kpT, vpT, opT);
    gemm_qkv_kernel<<<dim3(64, 4, 3), blk, 0, stream>>>(qb, kb, vb, qpT, kpT, vpT,
                                                        qsb, ksb, vsb);
    gemm512<0><<<dim3(1, 8), blk, 0, stream>>>(context, cp, cs, NG);
    chunk_sums_w_kernel<<<dim3(NBH, NCH), blk, 0, stream>>>(ksb, vsb, cs, wb, Mc, Nc);
    scan_kernel<<<dim3(NBH * NG), blk, 0, stream>>>(wb, nb);
    scan_chunks_kernel<<<dim3(NBH * 2), blk, 0, stream>>>(Mc, Nc);
    pass12_kernel<<<dim3(NBH, NCH), blk, 0, stream>>>(qsb, ksb, wb, nb, Mc, vsb, Nc, ohb);
    gemm_out_kernel<<<dim3(64, 8), blk, 0, stream>>>(ohb, opT, out);
}

// Round 9
// 151.863 us; speedup vs baseline: 5.1458x; 1.0995x over previous
//
#include <hip/hip_runtime.h>
#include <hip/hip_bf16.h>

#define NB 4
#define SL 2048
#define NG 16
#define NH 8
#define DH 64
#define NBH (NB * NH)
#define NCH (SL / 64)  // 32 chunks of 64

typedef __attribute__((ext_vector_type(8))) short bh8;
typedef __attribute__((ext_vector_type(4))) float fx4;

__device__ __forceinline__ ushort f2bf(float x) {
    union { float f; unsigned u; } v; v.f = x;
    const unsigned r = v.u + 0x7fffu + ((v.u >> 16) & 1u);  // RNE
    return (ushort)(r >> 16);
}
__device__ __forceinline__ float b2f(ushort u) {
    union { unsigned u; float f; } v; v.u = ((unsigned)u) << 16;
    return v.f;
}
__device__ __forceinline__ bh8 pack8(float4 lo, float4 hi) {
    bh8 r;
    r[0] = (short)f2bf(lo.x); r[1] = (short)f2bf(lo.y);
    r[2] = (short)f2bf(lo.z); r[3] = (short)f2bf(lo.w);
    r[4] = (short)f2bf(hi.x); r[5] = (short)f2bf(hi.y);
    r[6] = (short)f2bf(hi.z); r[7] = (short)f2bf(hi.w);
    return r;
}
__device__ __forceinline__ void unpack8(bh8 v, float4& lo, float4& hi) {
    lo.x = b2f((ushort)v[0]); lo.y = b2f((ushort)v[1]);
    lo.z = b2f((ushort)v[2]); lo.w = b2f((ushort)v[3]);
    hi.x = b2f((ushort)v[4]); hi.y = b2f((ushort)v[5]);
    hi.z = b2f((ushort)v[6]); hi.w = b2f((ushort)v[7]);
}

// ---------------------------------------------------------------------------
// Four weights (512x512 f32 [e][d]) -> bf16 transposed [d][e].  grid (16,16,4)
// ---------------------------------------------------------------------------
__global__ __launch_bounds__(256) void convT512_4(const float* __restrict__ w0,
                                                  const float* __restrict__ w1,
                                                  const float* __restrict__ w2,
                                                  const float* __restrict__ w3,
                                                  ushort* __restrict__ o0,
                                                  ushort* __restrict__ o1,
                                                  ushort* __restrict__ o2,
                                                  ushort* __restrict__ o3) {
    const int z = blockIdx.z;
    const float* W = (z == 0) ? w0 : (z == 1) ? w1 : (z == 2) ? w2 : w3;
    ushort* WT = (z == 0) ? o0 : (z == 1) ? o1 : (z == 2) ? o2 : o3;
    __shared__ float tile[32][33];
    const int bx = blockIdx.x * 32, by = blockIdx.y * 32;
    const int tx = threadIdx.x & 31, ty = threadIdx.x >> 5;
#pragma unroll
    for (int p = 0; p < 4; ++p)
        tile[ty + p * 8][tx] = W[(size_t)(by + ty + p * 8) * 512 + bx + tx];
    __syncthreads();
#pragma unroll
    for (int p = 0; p < 4; ++p)
        WT[(size_t)(bx + ty + p * 8) * 512 + by + tx] = f2bf(tile[tx][ty + p * 8]);
}

// ---------------------------------------------------------------------------
// QKV MFMA GEMM with FUSED f32->bf16 of A (reg-staged A, global_load_lds B).
// A (8192x512 f32) @ BT^T (512x512 bf16 [n][k]) -> bf16 heads layout.
// 128x128 tile, BK=32, double-buffered LDS, one barrier per K-step.
// grid (64, 4, 3) = 768 blocks -> 3 blocks/CU.
// ---------------------------------------------------------------------------
__global__ __launch_bounds__(256, 3) void gemm_qkv_kernel(
    const float* __restrict__ qf, const float* __restrict__ kf,
    const float* __restrict__ vf, const ushort* __restrict__ qpT,
    const ushort* __restrict__ kpT, const ushort* __restrict__ vpT,
    ushort* __restrict__ qsb, ushort* __restrict__ ksb, ushort* __restrict__ vsb) {
    const int z = blockIdx.z;
    const float* A32 = (z == 0) ? qf : (z == 1) ? kf : vf;
    const ushort* BT = (z == 0) ? qpT : (z == 1) ? kpT : vpT;
    ushort* out = (z == 0) ? qsb : (z == 1) ? ksb : vsb;

    __shared__ __align__(16) ushort As[2][128 * 32];
    __shared__ __align__(16) ushort Bs[2][128 * 32];
    const int t = threadIdx.x;
    const int lane = t & 63, w = t >> 6;
    const int bm = blockIdx.x * 128, bn = blockIdx.y * 128;
    // A staging: lane covers LDS elems e0=w*1024+lane*8 and e1=e0+512
    const int e0 = w * 1024 + lane * 8;
    const int e1 = e0 + 512;
    const int ar0 = bm + (e0 >> 5), ac0 = e0 & 31;
    const int ar1 = bm + (e1 >> 5);
    // B staging via global_load_lds (bf16 source)
    const size_t b0 = (size_t)(bn + (e0 >> 5)) * 512 + ac0;
    const size_t b1 = (size_t)(bn + (e1 >> 5)) * 512 + ac0;
    const int wr = w >> 1, wc = w & 1;
    const int fr = lane & 15, kg = lane >> 4;
    const int aoff = (wr * 64 + fr) * 32 + kg * 8;
    const int boff = (wc * 64 + fr) * 32 + kg * 8;
    fx4 acc[4][4] = {};
    float4 a00, a01, a10, a11;

#define LOADA(kk)                                                              \
    do {                                                                       \
        a00 = *(const float4*)&A32[(size_t)ar0 * 512 + (kk) + ac0];            \
        a01 = *(const float4*)&A32[(size_t)ar0 * 512 + (kk) + ac0 + 4];        \
        a10 = *(const float4*)&A32[(size_t)ar1 * 512 + (kk) + ac0];            \
        a11 = *(const float4*)&A32[(size_t)ar1 * 512 + (kk) + ac0 + 4];        \
    } while (0)
#define WRITEA(buf)                                                            \
    do {                                                                       \
        *(bh8*)&As[buf][e0] = pack8(a00, a01);                                 \
        *(bh8*)&As[buf][e1] = pack8(a10, a11);                                 \
    } while (0)
#define STAGEB(buf, kk)                                                        \
    do {                                                                       \
        __builtin_amdgcn_global_load_lds(                                      \
            (const __attribute__((address_space(1))) void*)(BT + b0 + (kk)),   \
            (__attribute__((address_space(3))) void*)&Bs[buf][w * 1024], 16, 0, 0); \
        __builtin_amdgcn_global_load_lds(                                      \
            (const __attribute__((address_space(1))) void*)(BT + b1 + (kk)),   \
            (__attribute__((address_space(3))) void*)&Bs[buf][w * 1024 + 512], 16, 0, 0); \
    } while (0)

    LOADA(0);
    STAGEB(0, 0);
    WRITEA(0);
    __syncthreads();
    int cur = 0;
    for (int k0 = 0; k0 < 512; k0 += 32) {
        if (k0 + 32 < 512) {
            LOADA(k0 + 32);       // issue early: hides under MFMA
            STAGEB(cur ^ 1, k0 + 32);
        }
        bh8 af[4], bf[4];
#pragma unroll
        for (int m = 0; m < 4; ++m) af[m] = *(const bh8*)&As[cur][aoff + m * 512];
#pragma unroll
        for (int nn = 0; nn < 4; ++nn) bf[nn] = *(const bh8*)&Bs[cur][boff + nn * 512];
#pragma unroll
        for (int m = 0; m < 4; ++m)
#pragma unroll
            for (int nn = 0; nn < 4; ++nn)
                acc[m][nn] = __builtin_amdgcn_mfma_f32_16x16x32_bf16(
                    af[m], bf[nn], acc[m][nn], 0, 0, 0);
        if (k0 + 32 < 512) WRITEA(cur ^ 1);  // write late: loads had MFMA to fly
        __syncthreads();
        cur ^= 1;
    }
#undef LOADA
#undef WRITEA
#undef STAGEB
#pragma unroll
    for (int m = 0; m < 4; ++m)
#pragma unroll
        for (int nn = 0; nn < 4; ++nn)
#pragma unroll
            for (int j = 0; j < 4; ++j) {
                const int r = bm + wr * 64 + m * 16 + kg * 4 + j;
                const int cc = bn + wc * 64 + nn * 16 + fr;
                const int b = r >> 11, i = r & 2047;  // M rows = B*SL, SL=2048
                out[(((size_t)(b * NH) + (cc >> 6)) * SL + i) * DH + (cc & 63)] =
                    f2bf(acc[m][nn][j]);
            }
}

// ---------------------------------------------------------------------------
// Output MFMA GEMM: ohb (8192x512 bf16) @ opT^T -> f32 plain.
// 128x64 tile -> grid (64, 8) = 512 blocks = 2 blocks/CU.
// ---------------------------------------------------------------------------
__global__ __launch_bounds__(256) void gemm_out_kernel(const ushort* __restrict__ A,
                                                       const ushort* __restrict__ BT,
                                                       float* __restrict__ out) {
    __shared__ __align__(16) ushort As[2][128 * 32];
    __shared__ __align__(16) ushort Bs[2][64 * 32];
    const int t = threadIdx.x;
    const int lane = t & 63, w = t >> 6;
    const int bm = blockIdx.x * 128, bn = blockIdx.y * 64;
    const int e0 = w * 1024 + lane * 8;
    const int e1 = e0 + 512;
    const int r0 = e0 >> 5, c0 = e0 & 31;
    const int r1 = e1 >> 5, c1 = e1 & 31;
    const size_t a0 = (size_t)(bm + r0) * 512 + c0;
    const size_t a1 = (size_t)(bm + r1) * 512 + c1;
    const int eb = w * 512 + lane * 8;
    const int rb = eb >> 5, cbc = eb & 31;
    const size_t b0 = (size_t)(bn + rb) * 512 + cbc;
    const int fr = lane & 15, kg = lane >> 4;
    const int aoff = (w * 32 + fr) * 32 + kg * 8;
    const int boff = fr * 32 + kg * 8;
    fx4 acc[2][4] = {};

#define STAGE_O(buf, kk)                                                           \
    do {                                                                           \
        __builtin_amdgcn_global_load_lds(                                          \
            (const __attribute__((address_space(1))) void*)(A + a0 + (kk)),        \
            (__attribute__((address_space(3))) void*)&As[buf][w * 1024], 16, 0, 0);\
        __builtin_amdgcn_global_load_lds(                                          \
            (const __attribute__((address_space(1))) void*)(A + a1 + (kk)),        \
            (__attribute__((address_space(3))) void*)&As[buf][w * 1024 + 512], 16, 0, 0);\
        __builtin_amdgcn_global_load_lds(                                          \
            (const __attribute__((address_space(1))) void*)(BT + b0 + (kk)),       \
            (__attribute__((address_space(3))) void*)&Bs[buf][w * 512], 16, 0, 0); \
    } while (0)

    STAGE_O(0, 0);
    __syncthreads();
    int cur = 0;
    for (int k0 = 0; k0 < 512; k0 += 32) {
        if (k0 + 32 < 512) STAGE_O(cur ^ 1, k0 + 32);
        bh8 af[2], bf[4];
#pragma unroll
        for (int m = 0; m < 2; ++m) af[m] = *(const bh8*)&As[cur][aoff + m * 512];
#pragma unroll
        for (int nn = 0; nn < 4; ++nn) bf[nn] = *(const bh8*)&Bs[cur][boff + nn * 512];
#pragma unroll
        for (int m = 0; m < 2; ++m)
#pragma unroll
            for (int nn = 0; nn < 4; ++nn)
                acc[m][nn] = __builtin_amdgcn_mfma_f32_16x16x32_bf16(
                    af[m], bf[nn], acc[m][nn], 0, 0, 0);
        __syncthreads();
        cur ^= 1;
    }
#undef STAGE_O
#pragma unroll
    for (int m = 0; m < 2; ++m)
#pragma unroll
        for (int nn = 0; nn < 4; ++nn)
#pragma unroll
            for (int j = 0; j < 4; ++j) {
                const int r = bm + w * 32 + m * 16 + kg * 4 + j;
                const int cc = bn + nn * 16 + fr;
                out[(size_t)r * 512 + cc] = acc[m][nn][j];
            }
}

// ---------------------------------------------------------------------------
// f32 GEMM for the tiny context projection (64 rows).  MODE 0 heads layout.
// ---------------------------------------------------------------------------
template <int MODE>
__global__ __launch_bounds__(256) void gemm512(const float* __restrict__ X,
                                               const float* __restrict__ Wm,
                                               float* __restrict__ out, int n) {
    __shared__ float As[16][65];
    __shared__ float Bs[16][64];
    const int t = threadIdx.x;
    const int rm = blockIdx.x * 64;
    const int cn = blockIdx.y * 64;
    const int tm = t >> 4, tn = t & 15;
    const int arow = t >> 2, ak = (t & 3) << 2;
    const int bk = t >> 4, bc = (t & 15) << 2;
    float acc[4][4] = {};
    for (int k0 = 0; k0 < 512; k0 += 16) {
        float4 av = *(const float4*)&X[(size_t)(rm + arow) * 512 + k0 + ak];
        float4 bv = *(const float4*)&Wm[(size_t)(k0 + bk) * 512 + cn + bc];
        __syncthreads();
        As[ak + 0][arow] = av.x;
        As[ak + 1][arow] = av.y;
        As[ak + 2][arow] = av.z;
        As[ak + 3][arow] = av.w;
        *(float4*)&Bs[bk][bc] = bv;
        __syncthreads();
#pragma unroll
        for (int kk = 0; kk < 16; ++kk) {
            float a0 = As[kk][tm * 4 + 0], a1 = As[kk][tm * 4 + 1];
            float a2 = As[kk][tm * 4 + 2], a3 = As[kk][tm * 4 + 3];
            float4 b = *(const float4*)&Bs[kk][tn * 4];
            acc[0][0] += a0 * b.x; acc[0][1] += a0 * b.y; acc[0][2] += a0 * b.z; acc[0][3] += a0 * b.w;
            acc[1][0] += a1 * b.x; acc[1][1] += a1 * b.y; acc[1][2] += a1 * b.z; acc[1][3] += a1 * b.w;
            acc[2][0] += a2 * b.x; acc[2][1] += a2 * b.y; acc[2][2] += a2 * b.z; acc[2][3] += a2 * b.w;
            acc[3][0] += a3 * b.x; acc[3][1] += a3 * b.y; acc[3][2] += a3 * b.z; acc[3][3] += a3 * b.w;
        }
    }
#pragma unroll
    for (int j = 0; j < 4; ++j) {
        const int r = rm + tm * 4 + j;
#pragma unroll
        for (int jj = 0; jj < 4; ++jj) {
            const int cc = cn + tn * 4 + jj;
            if (MODE == 0) {
                const int b = r / n, i = r % n;
                out[(((size_t)(b * NH) + (cc >> 6)) * n + i) * DH + (cc & 63)] = acc[j][jj];
            } else {
                out[(size_t)r * 512 + cc] = acc[j][jj];
            }
        }
    }
}

// ---------------------------------------------------------------------------
// Fused: W = exp(Ks@Cs^T) (written to wb) + per-chunk sums M_c, N_c.
// grid (NBH, NCH).  Vectorized bf16 unpack.
// ---------------------------------------------------------------------------
__global__ __launch_bounds__(256) void chunk_sums_w_kernel(
    const ushort* __restrict__ ksb, const ushort* __restrict__ vsb,
    const float* __restrict__ cs, float* __restrict__ wb,
    float* __restrict__ Mc, float* __restrict__ Nc) {
    const int bh = blockIdx.x, c = blockIdx.y;
    __shared__ float Ks[64 * 64];
    __shared__ float Vs[64 * 64];
    __shared__ float Ws[64 * 16];
    __shared__ float Cs[16][65];
    const int t = threadIdx.x;
    const ushort* kbase = ksb + ((size_t)bh * SL + c * 64) * DH;
    const ushort* vbase = vsb + ((size_t)bh * SL + c * 64) * DH;
#pragma unroll
    for (int p = 0; p < 2; ++p) {
        const int idx = (p * 256 + t) * 8;
        float4 lo, hi;
        unpack8(*(const bh8*)&kbase[idx], lo, hi);
        *(float4*)&Ks[idx] = lo; *(float4*)&Ks[idx + 4] = hi;
        unpack8(*(const bh8*)&vbase[idx], lo, hi);
        *(float4*)&Vs[idx] = lo; *(float4*)&Vs[idx + 4] = hi;
    }
    {
        const int idx = t * 4;
        const float4 cv = *(const float4*)&cs[(size_t)bh * NG * DH + idx];
        const int g = idx >> 6, e = idx & 63;
        Cs[g][e + 0] = cv.x; Cs[g][e + 1] = cv.y; Cs[g][e + 2] = cv.z; Cs[g][e + 3] = cv.w;
    }
    __syncthreads();
    {
        const int i = (t * 4) >> 4, g0 = (t * 4) & 15;
        float d0 = 0.f, d1 = 0.f, d2 = 0.f, d3 = 0.f;
#pragma unroll 8
        for (int e = 0; e < 64; ++e) {
            const float kv = Ks[i * 64 + e];
            d0 += kv * Cs[g0 + 0][e];
            d1 += kv * Cs[g0 + 1][e];
            d2 += kv * Cs[g0 + 2][e];
            d3 += kv * Cs[g0 + 3][e];
        }
        float4 wv;
        wv.x = expf(d0); wv.y = expf(d1); wv.z = expf(d2); wv.w = expf(d3);
        *(float4*)&Ws[i * 16 + g0] = wv;
        *(float4*)&wb[((size_t)bh * SL + c * 64 + i) * NG + g0] = wv;
    }
    __syncthreads();
    const int e = t >> 2, g0 = (t & 3) * 4;
    float m0 = 0.f, m1 = 0.f, m2 = 0.f, m3 = 0.f;
#pragma unroll 8
    for (int i = 0; i < 64; ++i) {
        const float kv = Ks[i * 64 + e];
        const float4 w = *(const float4*)&Ws[i * 16 + g0];
        m0 += kv * w.x; m1 += kv * w.y; m2 += kv * w.z; m3 += kv * w.w;
    }
    const int g2 = t >> 4, e2 = (t & 15) * 4;
    float n0 = 0.f, n1 = 0.f, n2 = 0.f, n3 = 0.f;
#pragma unroll 8
    for (int i = 0; i < 64; ++i) {
        const float wv = Ws[i * 16 + g2];
        const float4 vv = *(const float4*)&Vs[i * 64 + e2];
        n0 += wv * vv.x; n1 += wv * vv.y; n2 += wv * vv.z; n3 += wv * vv.w;
    }
    float* mo = Mc + ((size_t)(bh * NCH + c) * 64 + e) * 16 + g0;
    mo[0] = m0; mo[1] = m1; mo[2] = m2; mo[3] = m3;
    float* no = Nc + ((size_t)(bh * NCH + c) * 16 + g2) * 64 + e2;
    no[0] = n0; no[1] = n1; no[2] = n2; no[3] = n3;
}

// ---------------------------------------------------------------------------
// Merged scans.  bid < NBH*NG (=512): inclusive cumsum nb over s of wb.
// bid >= 512: in-place exclusive chunk-scan of Mc/Nc (64 blocks, prefetched).
// ---------------------------------------------------------------------------
__global__ __launch_bounds__(256) void scans_kernel(const float* __restrict__ wb,
                                                    float* __restrict__ nb,
                                                    float* __restrict__ Mc,
                                                    float* __restrict__ Nc) {
    const int bid = blockIdx.x;
    const int t = threadIdx.x;
    if (bid < NBH * NG) {
        const int bh = bid >> 4, g = bid & 15;
        __shared__ float sw[2048];
        __shared__ float sp[256];
        for (int p = 0; p < 8; ++p) {
            const int s = p * 256 + t;
            sw[s] = wb[((size_t)bh * SL + s) * NG + g];
        }
        __syncthreads();
        float loc[8];
        float run = 0.f;
#pragma unroll
        for (int j = 0; j < 8; ++j) { run += sw[t * 8 + j]; loc[j] = run; }
        sp[t] = run;
        __syncthreads();
        for (int off = 1; off < 256; off <<= 1) {
            const float v = sp[t];
            const float add = (t >= off) ? sp[t - off] : 0.f;
            __syncthreads();
            sp[t] = v + add;
            __syncthreads();
        }
        const float offs = (t > 0) ? sp[t - 1] : 0.f;
#pragma unroll
        for (int j = 0; j < 8; ++j)
            nb[(size_t)bid * SL + t * 8 + j] = offs + loc[j];
    } else {
        const int idx = bid - NBH * NG;
        const int bh = idx >> 1;
        float* base = ((idx & 1) ? Nc : Mc) + (size_t)bh * NCH * 1024;
        float4 run = make_float4(0.f, 0.f, 0.f, 0.f);
        float4 nxt = *(float4*)&base[t * 4];
        for (int c = 0; c < NCH; ++c) {
            const float4 v = nxt;
            if (c + 1 < NCH) nxt = *(float4*)&base[(c + 1) * 1024 + t * 4];
            *(float4*)&base[c * 1024 + t * 4] = run;
            run.x += v.x; run.y += v.y; run.z += v.z; run.w += v.w;
        }
    }
}

// ---------------------------------------------------------------------------
// pass1c: logits = causal(QK^T)@W + Q@P, /n, softmax over g, c = p/(sum*n)
// grid (NBH, NCH).  Vectorized bf16 staging.
// ---------------------------------------------------------------------------
__global__ __launch_bounds__(256) void pass1c_kernel(const ushort* __restrict__ qsb,
                                                     const ushort* __restrict__ ksb,
                                                     const float* __restrict__ wb,
                                                     const float* __restrict__ nb,
                                                     const float* __restrict__ Mc,
                                                     float* __restrict__ cb) {
    const int bh = blockIdx.x;
    const int r = blockIdx.y;
    const int s0 = r * 64;
    __shared__ float Qs[64][65];
    __shared__ float Kt[64][65];
    __shared__ float At[64][65];
    __shared__ float Wt[64 * 16];
    __shared__ float Pt[64 * 16];
    __shared__ float Lg[64][17];
    const int t = threadIdx.x;
    const int am = t >> 4, an = t & 15;
    const ushort* qbase = qsb + ((size_t)bh * SL + s0) * DH;
    const ushort* kbase = ksb + ((size_t)bh * SL + s0) * DH;
#pragma unroll
    for (int p = 0; p < 2; ++p) {
        const int idx = (p * 256 + t) * 8;
        const int row = idx >> 6, col = idx & 63;
        float4 lo, hi;
        unpack8(*(const bh8*)&qbase[idx], lo, hi);
        *(float4*)&Qs[row][col] = lo; *(float4*)&Qs[row][col + 4] = hi;
        unpack8(*(const bh8*)&kbase[idx], lo, hi);
        *(float4*)&Kt[row][col] = lo; *(float4*)&Kt[row][col + 4] = hi;
    }
    *(float4*)&Wt[t * 4] = *(const float4*)&wb[((size_t)bh * SL + s0) * NG + t * 4];
    *(float4*)&Pt[t * 4] = *(const float4*)&Mc[(size_t)(bh * NCH + r) * 1024 + t * 4];
    __syncthreads();
    float a[4][4] = {};
#pragma unroll 8
    for (int e = 0; e < 64; ++e) {
        float qv[4], kv[4];
#pragma unroll
        for (int j = 0; j < 4; ++j) qv[j] = Qs[am * 4 + j][e];
#pragma unroll
        for (int jj = 0; jj < 4; ++jj) kv[jj] = Kt[an * 4 + jj][e];
#pragma unroll
        for (int j = 0; j < 4; ++j)
#pragma unroll
            for (int jj = 0; jj < 4; ++jj) a[j][jj] += qv[j] * kv[jj];
    }
#pragma unroll
    for (int j = 0; j < 4; ++j)
#pragma unroll
        for (int jj = 0; jj < 4; ++jj) {
            if (an * 4 + jj > am * 4 + j) a[j][jj] = 0.f;
            At[am * 4 + j][an * 4 + jj] = a[j][jj];
        }
    __syncthreads();
    float lg[4] = {0.f, 0.f, 0.f, 0.f};
#pragma unroll 8
    for (int ii = 0; ii < 64; ++ii) {
        const float wv = Wt[ii * 16 + an];
#pragma unroll
        for (int j = 0; j < 4; ++j) lg[j] += At[am * 4 + j][ii] * wv;
    }
#pragma unroll 8
    for (int e = 0; e < 64; ++e) {
        const float pv = Pt[e * 16 + an];
#pragma unroll
        for (int j = 0; j < 4; ++j) lg[j] += Qs[am * 4 + j][e] * pv;
    }
#pragma unroll
    for (int j = 0; j < 4; ++j) Lg[am * 4 + j][an] = lg[j];
    __syncthreads();
    if (t < 64) {
        const int s = s0 + t;
        const float* nbase = nb + (size_t)bh * NG * SL + s;
        float nv[16], l[16];
        float mx = -1e30f;
#pragma unroll
        for (int g = 0; g < 16; ++g) {
            nv[g] = nbase[(size_t)g * SL];
            l[g] = Lg[t][g] / nv[g];
            mx = fmaxf(mx, l[g]);
        }
        float sum = 0.f;
#pragma unroll
        for (int g = 0; g < 16; ++g) { l[g] = expf(l[g] - mx); sum += l[g]; }
        const float inv = 1.f / sum;
#pragma unroll
        for (int g = 0; g < 16; ++g)
            cb[((size_t)bh * SL + s) * NG + g] = l[g] * inv / nv[g];
    }
}

// ---------------------------------------------------------------------------
// pass2c: out = C@U + causal(C W^T)@V  -> ohb (B,S,512) bf16
// grid (NBH, NCH).  ~45 KB LDS -> 3 blocks/CU.
// ---------------------------------------------------------------------------
__global__ __launch_bounds__(256) void pass2c_kernel(const float* __restrict__ cb,
                                                     const float* __restrict__ wb,
                                                     const ushort* __restrict__ vsb,
                                                     const float* __restrict__ Nc,
                                                     ushort* __restrict__ ohb) {
    const int bh = blockIdx.x;
    const int b = bh >> 3, h = bh & 7;
    const int r = blockIdx.y;
    const int s0 = r * 64;
    __shared__ float Ct[64][17];
    __shared__ float Wt[64][17];
    __shared__ float Vt[64 * 64];
    __shared__ float St[64][65];
    __shared__ float Ut[16 * 64];
    const int t = threadIdx.x;
    const int am = t >> 4, an = t & 15;
    {
        const int idx = t * 4;
        const int row = idx >> 4, g0 = idx & 15;
        const float4 cv = *(const float4*)&cb[((size_t)bh * SL + s0) * NG + idx];
        Ct[row][g0 + 0] = cv.x; Ct[row][g0 + 1] = cv.y;
        Ct[row][g0 + 2] = cv.z; Ct[row][g0 + 3] = cv.w;
        const float4 wv = *(const float4*)&wb[((size_t)bh * SL + s0) * NG + idx];
        Wt[row][g0 + 0] = wv.x; Wt[row][g0 + 1] = wv.y;
        Wt[row][g0 + 2] = wv.z; Wt[row][g0 + 3] = wv.w;
    }
    const ushort* vbase = vsb + ((size_t)bh * SL + s0) * DH;
#pragma unroll
    for (int p = 0; p < 2; ++p) {
        const int idx = (p * 256 + t) * 8;
        float4 lo, hi;
        unpack8(*(const bh8*)&vbase[idx], lo, hi);
        *(float4*)&Vt[idx] = lo; *(float4*)&Vt[idx + 4] = hi;
    }
    *(float4*)&Ut[t * 4] = *(const float4*)&Nc[(size_t)(bh * NCH + r) * 1024 + t * 4];
    __syncthreads();
    float sv[4][4] = {};
#pragma unroll
    for (int g = 0; g < 16; ++g) {
        float cv[4], wv[4];
#pragma unroll
        for (int j = 0; j < 4; ++j) cv[j] = Ct[am * 4 + j][g];
#pragma unroll
        for (int jj = 0; jj < 4; ++jj) wv[jj] = Wt[an * 4 + jj][g];
#pragma unroll
        for (int j = 0; j < 4; ++j)
#pragma unroll
            for (int jj = 0; jj < 4; ++jj) sv[j][jj] += cv[j] * wv[jj];
    }
#pragma unroll
    for (int j = 0; j < 4; ++j)
#pragma unroll
        for (int jj = 0; jj < 4; ++jj) {
            if (an * 4 + jj > am * 4 + j) sv[j][jj] = 0.f;
            St[am * 4 + j][an * 4 + jj] = sv[j][jj];
        }
    __syncthreads();
    float acc[4][4] = {};
#pragma unroll
    for (int g = 0; g < 16; ++g) {
        const float4 u = *(const float4*)&Ut[g * 64 + an * 4];
        float cv[4];
#pragma unroll
        for (int j = 0; j < 4; ++j) cv[j] = Ct[am * 4 + j][g];
#pragma unroll
        for (int j = 0; j < 4; ++j) {
            acc[j][0] += cv[j] * u.x; acc[j][1] += cv[j] * u.y;
            acc[j][2] += cv[j] * u.z; acc[j][3] += cv[j] * u.w;
        }
    }
#pragma unroll 8
    for (int ii = 0; ii < 64; ++ii) {
        const float4 vv = *(const float4*)&Vt[ii * 64 + an * 4];
        float st[4];
#pragma unroll
        for (int j = 0; j < 4; ++j) st[j] = St[am * 4 + j][ii];
#pragma unroll
        for (int j = 0; j < 4; ++j) {
            acc[j][0] += st[j] * vv.x; acc[j][1] += st[j] * vv.y;
            acc[j][2] += st[j] * vv.z; acc[j][3] += st[j] * vv.w;
        }
    }
#pragma unroll
    for (int j = 0; j < 4; ++j) {
        const int s = s0 + am * 4 + j;
        ushort4 pk;
        pk.x = f2bf(acc[j][0]); pk.y = f2bf(acc[j][1]);
        pk.z = f2bf(acc[j][2]); pk.w = f2bf(acc[j][3]);
        *(ushort4*)&ohb[((size_t)b * SL + s) * 512 + h * DH + an * 4] = pk;
    }
}

// ---------------------------------------------------------------------------
extern "C" void kernel_launch(void* const* d_in, const int* in_sizes, int n_in,
                              void* d_out, int out_size, void* d_ws, size_t ws_size,
                              hipStream_t stream) {
    const float* query   = (const float*)d_in[0];
    const float* key     = (const float*)d_in[1];
    const float* value   = (const float*)d_in[2];
    const float* context = (const float*)d_in[3];
    const float* qp = (const float*)d_in[4];
    const float* kp = (const float*)d_in[5];
    const float* vp = (const float*)d_in[6];
    const float* op = (const float*)d_in[7];
    const float* cp = (const float*)d_in[8];
    float* out = (float*)d_out;

    // ---- workspace layout (~57 MB, no aliasing) ----
    ushort* qsb = (ushort*)d_ws;            // 4,194,304 ushorts each
    ushort* ksb = qsb + 4194304;
    ushort* vsb = ksb + 4194304;
    ushort* ohb = vsb + 4194304;
    ushort* qpT = ohb + 4194304;            // 262,144 each
    ushort* kpT = qpT + 262144;
    ushort* vpT = kpT + 262144;
    ushort* opT = vpT + 262144;
    float* fbase = (float*)(opT + 262144);
    float* cs = fbase;                      // 32,768
    float* wb = cs + 32768;                 // 1,048,576 each
    float* nb = wb + 1048576;
    float* Mc = nb + 1048576;
    float* Nc = Mc + 1048576;
    float* cb = Nc + 1048576;

    dim3 blk(256);
    convT512_4<<<dim3(16, 16, 4), blk, 0, stream>>>(qp, kp, vp, op, qpT, kpT, vpT, opT);
    gemm512<0><<<dim3(1, 8), blk, 0, stream>>>(context, cp, cs, NG);
    gemm_qkv_kernel<<<dim3(64, 4, 3), blk, 0, stream>>>(query, key, value,
                                                        qpT, kpT, vpT, qsb, ksb, vsb);
    chunk_sums_w_kernel<<<dim3(NBH, NCH), blk, 0, stream>>>(ksb, vsb, cs, wb, Mc, Nc);
    scans_kernel<<<dim3(NBH * NG + NBH * 2), blk, 0, stream>>>(wb, nb, Mc, Nc);
    pass1c_kernel<<<dim3(NBH, NCH), blk, 0, stream>>>(qsb, ksb, wb, nb, Mc, cb);
    pass2c_kernel<<<dim3(NBH, NCH), blk, 0, stream>>>(cb, wb, vsb, Nc, ohb);
    gemm_out_kernel<<<dim3(64, 8), blk, 0, stream>>>(ohb, opT, out);
}